// Round 1
// baseline (2801.588 us; speedup 1.0000x reference)
//
#include <hip/hip_runtime.h>
#include <math.h>

typedef float f32x4 __attribute__((ext_vector_type(4)));
typedef short s16x8 __attribute__((ext_vector_type(8)));
typedef unsigned short u16;
typedef unsigned int u32;

#define MFMA16(a,b,c) __builtin_amdgcn_mfma_f32_16x16x32_bf16((a),(b),(c),0,0,0)
#define AS1 __attribute__((address_space(1)))
#define AS3 __attribute__((address_space(3)))

__device__ __forceinline__ void dma16(const u16* g, u16* l){
  __builtin_amdgcn_global_load_lds((const AS1 u32*)g, (AS3 u32*)l, 16, 0, 0);
}

__device__ __forceinline__ float bf2f(u16 u){
  union { unsigned int i; float f; } v; v.i = ((unsigned int)u)<<16; return v.f;
}
__device__ __forceinline__ u16 f2bf(float f){
  union { float f; unsigned int i; } v; v.f = f;
  unsigned int x = v.i;
  return (u16)((x + 0x7fffu + ((x>>16)&1u))>>16);
}

enum { EPI_QKV=0, EPI_PINV=1, EPI_BIAS_RES=2, EPI_BIAS_GELU=3 };

// ---------------------------------------------------------------------------
// kgemm: BM=128, BN=64, BK=32 (N=256 outputs: RES / RES2).
// ---------------------------------------------------------------------------
template<int EPI>
__global__ __launch_bounds__(256)
void kgemm(const u16* __restrict__ A, const u16* __restrict__ BT, int K, int lda, int ldb,
           const float* __restrict__ bias, const float* __restrict__ base,
           float* __restrict__ resout,
           u16* __restrict__ outb, int ldc)
{
  __shared__ __align__(16) u16 As[128*32];
  __shared__ __align__(16) u16 Bs[64*32];
  const int tid = threadIdx.x;
  const int w = tid>>6, l = tid&63, q = l>>4, ln = l&15;
  const int m0 = blockIdx.x*128, n0 = blockIdx.y*64;
  const int lrow = l>>2, lch = l&3;

  f32x4 acc[2][4];
  #pragma unroll
  for (int i=0;i<2;i++)
    #pragma unroll
    for (int j=0;j<4;j++){ acc[i][j][0]=0.f; acc[i][j][1]=0.f; acc[i][j][2]=0.f; acc[i][j][3]=0.f; }

  for (int k0=0; k0<K; k0+=32){
    #pragma unroll
    for (int c=0;c<2;c++){
      int row = 32*w + 16*c + lrow;
      int gch = lch ^ ((row>>1)&3);
      dma16(A + (long)(m0+row)*lda + k0 + gch*8, &As[(32*w+16*c)*32]);
    }
    {
      int row = 16*w + lrow;
      int gch = lch ^ ((row>>1)&3);
      dma16(BT + (long)(n0+row)*ldb + k0 + gch*8, &Bs[(16*w)*32]);
    }
    __syncthreads();
    s16x8 af[2], bfr[4];
    #pragma unroll
    for (int mt=0;mt<2;mt++){
      int row = w*32 + mt*16 + ln;
      af[mt] = *(const s16x8*)&As[row*32 + ((q ^ ((row>>1)&3))<<3)];
    }
    #pragma unroll
    for (int nt=0;nt<4;nt++){
      int row = nt*16 + ln;
      bfr[nt] = *(const s16x8*)&Bs[row*32 + ((q ^ ((row>>1)&3))<<3)];
    }
    #pragma unroll
    for (int mt=0;mt<2;mt++)
      #pragma unroll
      for (int nt=0;nt<4;nt++)
        acc[mt][nt] = MFMA16(af[mt], bfr[nt], acc[mt][nt]);
    __syncthreads();
  }

  #pragma unroll
  for (int mt=0;mt<2;mt++)
  #pragma unroll
  for (int nt=0;nt<4;nt++)
  #pragma unroll
  for (int r=0;r<4;r++){
    int mrow = m0 + w*32 + mt*16 + q*4 + r;
    int ncol = n0 + nt*16 + ln;
    float v = acc[mt][nt][r];
    if (EPI==EPI_BIAS_RES){
      long idx = (long)mrow*ldc + ncol;
      resout[idx] = base[idx] + v + bias[ncol];
    } else {
      outb[(long)mrow*ldc + ncol] = f2bf(v);
    }
  }
}

// ---------------------------------------------------------------------------
// kgemm2: BM=128, BN=128, BK=32, 4x4 frags/wave; DMA staging + swizzle.
// ---------------------------------------------------------------------------
template<int EPI>
__global__ __launch_bounds__(256)
void kgemm2(const u16* __restrict__ A, const u16* __restrict__ BT, int K, int lda, int ldb,
            const float* __restrict__ bias, u16* __restrict__ outb, int ldc,
            u16* __restrict__ qo, u16* __restrict__ ko, u16* __restrict__ vo,
            u16* __restrict__ qlm, u16* __restrict__ klm)
{
  __shared__ __align__(16) u16 As[128*32];
  __shared__ __align__(16) u16 Bs[128*32];
  const int tid = threadIdx.x;
  const int w = tid>>6, wy = w>>1, wx = w&1, l = tid&63, q = l>>4, ln = l&15;
  const int m0 = blockIdx.x*128, n0 = blockIdx.y*128;
  const int lrow = l>>2, lch = l&3;

  f32x4 acc[4][4];
  #pragma unroll
  for (int i=0;i<4;i++)
    #pragma unroll
    for (int j=0;j<4;j++){ acc[i][j][0]=0.f; acc[i][j][1]=0.f; acc[i][j][2]=0.f; acc[i][j][3]=0.f; }

  for (int k0=0; k0<K; k0+=32){
    #pragma unroll
    for (int c=0;c<2;c++){
      int row = 32*w + 16*c + lrow;
      int gch = lch ^ ((row>>1)&3);
      dma16(A + (long)(m0+row)*lda + k0 + gch*8, &As[(32*w+16*c)*32]);
      dma16(BT + (long)(n0+row)*ldb + k0 + gch*8, &Bs[(32*w+16*c)*32]);
    }
    __syncthreads();
    s16x8 af[4], bfr[4];
    #pragma unroll
    for (int mt=0;mt<4;mt++){
      int row = wy*64 + mt*16 + ln;
      af[mt] = *(const s16x8*)&As[row*32 + ((q ^ ((row>>1)&3))<<3)];
    }
    #pragma unroll
    for (int nt=0;nt<4;nt++){
      int row = wx*64 + nt*16 + ln;
      bfr[nt] = *(const s16x8*)&Bs[row*32 + ((q ^ ((row>>1)&3))<<3)];
    }
    #pragma unroll
    for (int mt=0;mt<4;mt++)
      #pragma unroll
      for (int nt=0;nt<4;nt++)
        acc[mt][nt] = MFMA16(af[mt], bfr[nt], acc[mt][nt]);
    __syncthreads();
  }

  #pragma unroll
  for (int mt=0;mt<4;mt++)
  #pragma unroll
  for (int nt=0;nt<4;nt++){
    int ncol = n0 + wx*64 + nt*16 + ln;
    if (EPI==EPI_QKV){
      int sel = ncol>>8, hd = ncol&255, h = hd>>5, d = hd&31;
      u16* dst = sel==0 ? qo : (sel==1 ? ko : vo);
      float sc2 = (sel==0) ? 0.17677669529663689f : 1.f;   // dh^-0.5 on q
      float s = 0.f;
      #pragma unroll
      for (int r=0;r<4;r++){
        int mrow = m0 + wy*64 + mt*16 + q*4 + r;
        int b = mrow>>12, n = mrow&4095;
        float v = acc[mt][nt][r]*sc2;
        dst[(((long)(b*8+h)*4096 + n)<<5) + d] = f2bf(v);
        s += v;
      }
      if (sel < 2){
        s += __shfl_xor(s, 16);
        s += __shfl_xor(s, 32);
        if (q == 0){
          int mrow0 = m0 + wy*64 + mt*16;
          int b = mrow0>>12, grp = (mrow0&4095)>>4;
          u16* ldst = (sel==0) ? qlm : klm;
          ldst[(((long)(b*8+h)*256 + grp)<<5) + d] = f2bf(s*(1.0f/16.0f));
        }
      }
    } else { // EPI_BIAS_GELU
      #pragma unroll
      for (int r=0;r<4;r++){
        int mrow = m0 + wy*64 + mt*16 + q*4 + r;
        float x = acc[mt][nt][r] + bias[ncol];
        float g = 0.5f*x*(1.0f + erff(x*0.70710678118654752f));
        outb[(long)mrow*ldc + ncol] = f2bf(g);
      }
    }
  }
}

// ---------------------------------------------------------------------------
// Fused pinv megakernel building blocks (64x64 tiles, K=256, swizzled LDS)
// ---------------------------------------------------------------------------
__device__ __forceinline__ void gbar(unsigned* bar, unsigned need){
  __syncthreads();
  if (threadIdx.x == 0){
    __builtin_amdgcn_fence(__ATOMIC_RELEASE, "agent");
    __hip_atomic_fetch_add(bar, 1u, __ATOMIC_RELEASE, __HIP_MEMORY_SCOPE_AGENT);
    while (__hip_atomic_load(bar, __ATOMIC_RELAXED, __HIP_MEMORY_SCOPE_AGENT) < need)
      __builtin_amdgcn_s_sleep(4);
    __builtin_amdgcn_fence(__ATOMIC_ACQUIRE, "agent");
  }
  __syncthreads();
}

__device__ __forceinline__ void zero4(f32x4 (&a)[4]){
  #pragma unroll
  for (int j=0;j<4;j++){ a[j][0]=0.f; a[j][1]=0.f; a[j][2]=0.f; a[j][3]=0.f; }
}

// stage 64 rows x 64 cols (one K-chunk) of a 256-col row-major matrix, swizzled
__device__ __forceinline__ void stage64(const u16* __restrict__ P, int r0, int k0, u16* Ls){
  const int tid=threadIdx.x, w=tid>>6, l=tid&63, drow=l>>3, dch=l&7;
  #pragma unroll
  for (int c=0;c<2;c++){
    int rbase = w*16 + c*8;
    int row = rbase + drow;
    int gch = dch ^ ((row>>1)&7);
    dma16(P + (long)(r0+row)*256 + k0 + gch*8, &Ls[rbase*64]);
  }
}

__device__ __forceinline__ void gemm64(const u16* __restrict__ Ap, const u16* __restrict__ Bp,
                                       int m0, int n0, u16* As, u16* Bs, f32x4 (&acc)[4])
{
  const int tid=threadIdx.x, w=tid>>6, l=tid&63, q=l>>4, ln=l&15;
  for (int k0=0;k0<256;k0+=64){
    stage64(Ap, m0, k0, As);
    stage64(Bp, n0, k0, Bs);
    __syncthreads();
    #pragma unroll
    for (int kb=0;kb<2;kb++){
      int arow = w*16 + ln;
      s16x8 af = *(const s16x8*)&As[arow*64 + (((kb*4+q) ^ ((arow>>1)&7))<<3)];
      #pragma unroll
      for (int nt=0;nt<4;nt++){
        int brow = nt*16 + ln;
        s16x8 bfr = *(const s16x8*)&Bs[brow*64 + (((kb*4+q) ^ ((brow>>1)&7))<<3)];
        acc[nt] = MFMA16(af, bfr, acc[nt]);
      }
    }
    __syncthreads();
  }
}

// PAIR: W' = W@M and z' = z@M share the B tile -> stage B once
__device__ __forceinline__ void gemm64_pair(const u16* __restrict__ A1, const u16* __restrict__ A2,
                                            const u16* __restrict__ Bp, int m0, int n0,
                                            u16* As, u16* As2, u16* Bs,
                                            f32x4 (&accW)[4], f32x4 (&accZ)[4])
{
  const int tid=threadIdx.x, w=tid>>6, l=tid&63, q=l>>4, ln=l&15;
  for (int k0=0;k0<256;k0+=64){
    stage64(A1, m0, k0, As);
    stage64(A2, m0, k0, As2);
    stage64(Bp, n0, k0, Bs);
    __syncthreads();
    #pragma unroll
    for (int kb=0;kb<2;kb++){
      int arow = w*16 + ln;
      int aslot = (((kb*4+q) ^ ((arow>>1)&7))<<3);
      s16x8 af1 = *(const s16x8*)&As [arow*64 + aslot];
      s16x8 af2 = *(const s16x8*)&As2[arow*64 + aslot];
      #pragma unroll
      for (int nt=0;nt<4;nt++){
        int brow = nt*16 + ln;
        s16x8 bfr = *(const s16x8*)&Bs[brow*64 + (((kb*4+q) ^ ((brow>>1)&7))<<3)];
        accW[nt] = MFMA16(af1, bfr, accW[nt]);
        accZ[nt] = MFMA16(af2, bfr, accZ[nt]);
      }
    }
    __syncthreads();
  }
}

__device__ __forceinline__ void epi_store(u16* __restrict__ out, int m0, int n0,
                                          const f32x4 (&acc)[4], float sc){
  const int tid=threadIdx.x, w=tid>>6, l=tid&63, q=l>>4, ln=l&15;
  #pragma unroll
  for (int nt=0;nt<4;nt++)
  #pragma unroll
  for (int r=0;r<4;r++){
    int mrow = m0 + w*16 + q*4 + r, ncol = n0 + nt*16 + ln;
    out[(long)mrow*256 + ncol] = f2bf(acc[nt][r]*sc);
  }
}

__device__ __forceinline__ void epi_storeT(u16* __restrict__ out, int m0, const f32x4 (&acc)[4]){
  const int tid=threadIdx.x, w=tid>>6, l=tid&63, q=l>>4, ln=l&15;
  #pragma unroll
  for (int nt=0;nt<4;nt++)
  #pragma unroll
  for (int r=0;r<4;r++){
    int mrow = m0 + w*16 + q*4 + r, ncol = nt*16 + ln;
    out[(long)ncol*256 + mrow] = f2bf(acc[nt][r]);
  }
}

// ---------------------------------------------------------------------------
// kpinv_all: ks0w3 + W0 + 5x{S,M,PAIR} + 4 thin-tail stages, ONE launch.
// 512 wg, 2/CU co-resident (forced via __launch_bounds__), manual agent-scope
// generation barrier (monotonic counter; base passed per launch; zeroed by
// kcvtall each kernel_launch call so graph replay is safe).
// ---------------------------------------------------------------------------
__global__ __launch_bounds__(256,2)
void kpinv_all(const float* __restrict__ cs_p, float* __restrict__ scal,
               const float* __restrict__ num_p, const float* __restrict__ den_p,
               u16* __restrict__ w3T,
               const u16* __restrict__ X, const u16* __restrict__ z0,
               u16* __restrict__ WA, u16* __restrict__ WB,
               u16* __restrict__ Sb, u16* __restrict__ Mb,
               u16* __restrict__ zA, u16* __restrict__ zB,
               u16* __restrict__ aT, u16* __restrict__ bT,
               u16* __restrict__ g1T, u16* __restrict__ uT,
               unsigned* __restrict__ bar, unsigned bar_base)
{
  __shared__ __align__(16) char smraw[33024];   // max(3*8KB gemm slabs, 32.9KB lt)
  u16* As  = (u16*)smraw;
  u16* Bs  = (u16*)(smraw + 8192);
  u16* As2 = (u16*)(smraw + 16384);

  const int bid = blockIdx.x, tid = threadIdx.x;
  const int w = tid>>6, l = tid&63, q = l>>4, ln = l&15;
  unsigned need = bar_base;

  // ---- phase 0: scal (wg0) + w3T prep (wg 1..32) ----
  if (bid == 0){
    float* red = (float*)smraw;
    float m = 0.f;
    for (int i=tid;i<8192;i+=256){
      float s = 0.f;
      #pragma unroll
      for (int c=0;c<8;c++) s += cs_p[(long)c*8192 + i];
      m = fmaxf(m, s);
    }
    red[tid] = m; __syncthreads();
    for (int s=128;s>0;s>>=1){ if (tid<s) red[tid] = fmaxf(red[tid], red[tid+s]); __syncthreads(); }
    if (tid==0) scal[0] = 1.0f/red[0];
  } else if (bid <= 32){
    int bh = bid - 1;
    float (*lt)[257] = (float(*)[257])smraw;
    for (int i=tid;i<8192;i+=256){
      int m = i>>5, d = i&31;
      float sn = 0.f, sd = 0.f;
      #pragma unroll
      for (int c=0;c<8;c++){
        sn += num_p[((long)(c*32+bh))*8192 + i];
        sd += den_p[(c*32+bh)*256 + m];
      }
      lt[d][m] = sn/sd;
    }
    __syncthreads();
    u16* o = w3T + (long)bh*16384;
    for (int j=tid;j<16384;j+=256){
      int d = j>>8, m = j&255;
      o[j] = (d<32) ? f2bf(lt[d][m]) : (u16)0;
    }
  }
  need += 512; gbar(bar, need);
  const float s0 = scal[0];

  // tile coords for full 256x256 phases: 32 batches x (4x4) tiles
  const int bz = bid>>4, bx = bid&3, by = (bid>>2)&3;
  const int m0 = bx*64, n0 = by*64;
  const long boff = (long)bz*65536;

  f32x4 acc[4], acc2[4];

  // ---- W0 = s0 * (X @ X^T)  (scale in f32 epilogue) ----
  zero4(acc);
  gemm64(X+boff, X+boff, m0, n0, As, Bs, acc);
  epi_store(WA+boff, m0, n0, acc, s0);
  need += 512; gbar(bar, need);

  const u16 *Wi = WA, *zi = z0;
  u16 *Wo = WB, *zo = zA;
  for (int it=0; it<5; it++){
    // S = W @ W^T-conv
    zero4(acc);
    gemm64(Wi+boff, Wi+boff, m0, n0, As, Bs, acc);
    epi_store(Sb+boff, m0, n0, acc, 1.f);
    need += 512; gbar(bar, need);
    // M = 0.25(13I - 15W + 7S - S@W)
    zero4(acc);
    gemm64(Sb+boff, Wi+boff, m0, n0, As, Bs, acc);
    #pragma unroll
    for (int nt=0;nt<4;nt++)
    #pragma unroll
    for (int r=0;r<4;r++){
      int mrow = m0 + w*16 + q*4 + r, ncol = n0 + nt*16 + ln;
      long idx = boff + (long)mrow*256 + ncol;
      float wv = bf2f(Wi[idx]), sv = bf2f(Sb[idx]);
      Mb[idx] = f2bf(0.25f*(((mrow==ncol)?13.f:0.f) - 15.f*wv + 7.f*sv - acc[nt][r]));
    }
    need += 512; gbar(bar, need);
    // W' = W@M ; z' = z@M (shared B tile)
    zero4(acc); zero4(acc2);
    gemm64_pair(Wi+boff, zi+boff, Mb+boff, m0, n0, As, As2, Bs, acc, acc2);
    epi_store(Wo+boff, m0, n0, acc, 1.f);
    epi_store(zo+boff, m0, n0, acc2, 1.f);
    need += 512; gbar(bar, need);
    const u16* t = Wi; Wi = Wo; Wo = (u16*)t;
    zi = zo; zo = (zo == zA) ? zB : zA;
  }

  // ---- thin tail: 128 wgs (4 m-tiles x 32 batches); others idle at barriers ----
  const int  tz = bid>>2, tx = bid&3;
  const int  tm0 = tx*64;
  const bool tw = (bid < 128);
  const long wboff = (long)tz*65536, tboff = (long)tz*16384;

  if (tw){ // a = (W5 @ w3^T)^T
    zero4(acc);
    gemm64(Wi+wboff, w3T+tboff, tm0, 0, As, Bs, acc);
    epi_storeT(aT+tboff, tm0, acc);
  }
  need += 512; gbar(bar, need);
  if (tw){ // b = (W5 @ a^T)^T
    zero4(acc);
    gemm64(Wi+wboff, aT+tboff, tm0, 0, As, Bs, acc);
    epi_storeT(bT+tboff, tm0, acc);
  }
  need += 512; gbar(bar, need);
  if (tw){ // g1 = 0.25(13 w3 - 15 a + 7 b - W5@b)
    zero4(acc);
    gemm64(Wi+wboff, bT+tboff, tm0, 0, As, Bs, acc);
    #pragma unroll
    for (int nt=0;nt<4;nt++)
    #pragma unroll
    for (int r=0;r<4;r++){
      int mrow = tm0 + w*16 + q*4 + r, ncol = nt*16 + ln;
      long idxt = tboff + (long)ncol*256 + mrow;
      g1T[idxt] = f2bf(0.25f*(13.f*bf2f(w3T[idxt]) - 15.f*bf2f(aT[idxt]) + 7.f*bf2f(bT[idxt]) - acc[nt][r]));
    }
  }
  need += 512; gbar(bar, need);
  if (tw){ // u = s0 * z5 @ g1^T (thin: first 32 cols)
    zero4(acc);
    gemm64(zi+wboff, g1T+tboff, tm0, 0, As, Bs, acc);
    #pragma unroll
    for (int nt=0;nt<4;nt++)
    #pragma unroll
    for (int r=0;r<4;r++){
      int ncol = nt*16 + ln;
      if (ncol < 32){
        int mrow = tm0 + w*16 + q*4 + r;
        uT[(long)tz*8192 + (long)ncol*256 + mrow] = f2bf(acc[nt][r]*s0);
      }
    }
  }
}

// ---------------------------------------------------------------------------
// LayerNorm: one wave per row (256 cols), write bf16
// ---------------------------------------------------------------------------
__global__ __launch_bounds__(256)
void kln(const float* __restrict__ y, const float* __restrict__ g, const float* __restrict__ b,
         u16* __restrict__ out)
{
  int w = threadIdx.x>>6, l = threadIdx.x&63;
  long row = (long)blockIdx.x*4 + w;
  float4 v = ((const float4*)(y + row*256))[l];
  float s = v.x+v.y+v.z+v.w;
  #pragma unroll
  for (int m=1;m<64;m<<=1) s += __shfl_xor(s, m);
  float mu = s*(1.0f/256.0f);
  float dx=v.x-mu, dy=v.y-mu, dz=v.z-mu, dw=v.w-mu;
  float s2 = dx*dx+dy*dy+dz*dz+dw*dw;
  #pragma unroll
  for (int m=1;m<64;m<<=1) s2 += __shfl_xor(s2, m);
  float rs = rsqrtf(s2*(1.0f/256.0f) + 1e-5f);
  float4 gg = ((const float4*)g)[l];
  float4 bb = ((const float4*)b)[l];
  ushort4 o;
  o.x = f2bf(dx*rs*gg.x + bb.x);
  o.y = f2bf(dy*rs*gg.y + bb.y);
  o.z = f2bf(dz*rs*gg.z + bb.z);
  o.w = f2bf(dw*rs*gg.w + bb.w);
  *(ushort4*)(out + row*256 + l*4) = o;
}

// ---------------------------------------------------------------------------
// Merged attn2 + attn3v (independent; grid (16,32): x<8 attn2, x>=8 attn3v)
// ---------------------------------------------------------------------------
__global__ __launch_bounds__(256)
void kattn23(const u16* __restrict__ ql, const u16* __restrict__ kl,
             u16* __restrict__ X, u16* __restrict__ XT, float* __restrict__ cs_p,
             const u16* __restrict__ kk, const u16* __restrict__ vv,
             float* __restrict__ num_p, float* __restrict__ den_p)
{
  __shared__ __align__(16) u16 Pbuf[4][64][40];
  __shared__ __align__(16) u16 vT[32][40];
  __shared__ float qrow[32][33];
  __shared__ float psum[32][4];
  __shared__ float rsum[32];
  int bh = blockIdx.y;
  int tid = threadIdx.x, w = tid>>6, l = tid&63, q = l>>4, ln = l&15;

  if (blockIdx.x < 8){
    int r0 = blockIdx.x*32;
    int c = tid;
    #pragma unroll
    for (int i=0;i<4;i++){
      int e = c*4+i; int rr = e>>5, dd = e&31;
      qrow[rr][dd] = bf2f(ql[((long)bh*256 + r0+rr)*32 + dd]);
    }
    float kc[32];
    {
      const u16* kp = kl + ((long)bh*256 + c)*32;
      #pragma unroll
      for (int d=0;d<32;d++) kc[d] = bf2f(kp[d]);
    }
    __syncthreads();
    float er[32]; float colacc = 0.f;
    for (int r=0;r<32;r++){
      float s = 0.f;
      #pragma unroll
      for (int d=0;d<32;d++) s += qrow[r][d]*kc[d];
      float e = __expf(s);
      er[r] = e;
      float wsum = e;
      #pragma unroll
      for (int m=1;m<64;m<<=1) wsum += __shfl_xor(wsum, m);
      if (l==0) psum[r][w] = wsum;
    }
    __syncthreads();
    if (c<32) rsum[c] = psum[c][0]+psum[c][1]+psum[c][2]+psum[c][3];
    __syncthreads();
    for (int r=0;r<32;r++){
      float x = er[r]/rsum[r];
      u16 xb = f2bf(x);
      X [((long)bh*256 + r0+r)*256 + c] = xb;
      XT[((long)bh*256 + c)*256 + r0+r] = xb;
      colacc += x;
    }
    cs_p[(long)blockIdx.x*8192 + bh*256 + c] = colacc;
    return;
  }

  int chunk = blockIdx.x - 8;
  f32x4 z4; z4[0]=0.f; z4[1]=0.f; z4[2]=0.f; z4[3]=0.f;
  f32x4 acc[4][2]; f32x4 dacc[4];
  #pragma unroll
  for (int mt=0;mt<4;mt++){ dacc[mt]=z4; acc[mt][0]=z4; acc[mt][1]=z4; }
  const u16* qlb = ql + (long)bh*8192;
  const u16* kb  = kk + (long)bh*131072;
  const u16* vb  = vv + (long)bh*131072;
  int vn = tid>>3, vd = (tid&7)*4;
  for (int s=0;s<16;s++){
    int n0 = chunk*512 + s*32;
    ushort4 vx = *(const ushort4*)(vb + (long)(n0+vn)*32 + vd);
    vT[vd+0][vn]=vx.x; vT[vd+1][vn]=vx.y; vT[vd+2][vn]=vx.z; vT[vd+3][vn]=vx.w;
    __syncthreads();
    s16x8 bk[2];
    #pragma unroll
    for (int nt=0;nt<2;nt++) bk[nt] = *(const s16x8*)(kb + (long)(n0 + nt*16 + ln)*32 + q*8);
    #pragma unroll
    for (int mt=0;mt<4;mt++){
      s16x8 aq = *(const s16x8*)(qlb + (long)(w*64 + mt*16 + ln)*32 + q*8);
      #pragma unroll
      for (int nt=0;nt<2;nt++){
        f32x4 sf = MFMA16(aq, bk[nt], z4);
        f32x4 ef;
        #pragma unroll
        for (int r=0;r<4;r++) ef[r] = __expf(sf[r]);
        dacc[mt] += ef;
        #pragma unroll
        for (int r=0;r<4;r++) Pbuf[w][mt*16 + q*4 + r][nt*16 + ln] = f2bf(ef[r]);
      }
    }
    #pragma unroll
    for (int mt=0;mt<4;mt++){
      s16x8 ap = *(const s16x8*)&Pbuf[w][mt*16 + ln][q*8];
      #pragma unroll
      for (int nt=0;nt<2;nt++){
        s16x8 bv = *(const s16x8*)&vT[nt*16 + ln][q*8];
        acc[mt][nt] = MFMA16(ap, bv, acc[mt][nt]);
      }
    }
    __syncthreads();
  }
  #pragma unroll
  for (int mt=0;mt<4;mt++)
    #pragma unroll
    for (int r=0;r<4;r++){
      float x = dacc[mt][r];
      x += __shfl_xor(x,1); x += __shfl_xor(x,2); x += __shfl_xor(x,4); x += __shfl_xor(x,8);
      dacc[mt][r] = x;
    }
  long pbase = (long)(chunk*32 + bh);
  #pragma unroll
  for (int mt=0;mt<4;mt++)
    #pragma unroll
    for (int nt=0;nt<2;nt++)
      #pragma unroll
      for (int r=0;r<4;r++){
        int mg = w*64 + mt*16 + q*4 + r;
        num_p[pbase*8192 + (long)mg*32 + nt*16 + ln] = acc[mt][nt][r];
      }
  if (ln==0){
    #pragma unroll
    for (int mt=0;mt<4;mt++)
      #pragma unroll
      for (int r=0;r<4;r++)
        den_p[pbase*256 + w*64 + mt*16 + q*4 + r] = dacc[mt][r];
  }
}

// ---------------------------------------------------------------------------
// attn1 fused + depthwise residual conv
// ---------------------------------------------------------------------------
__global__ __launch_bounds__(256)
void kattn1u(const u16* __restrict__ qq, const u16* __restrict__ kl, const u16* __restrict__ uT,
             const u16* __restrict__ vv, const float* __restrict__ rw,
             u16* __restrict__ aoutb)
{
  int nch = blockIdx.x, bh = blockIdx.y;
  int b = bh>>3, h = bh&7;
  int tid = threadIdx.x, w = tid>>6, l = tid&63, q = l>>4, ln = l&15;
  __shared__ __align__(16) u16 Pbuf[4][32][40];
  __shared__ __align__(16) u16 vtile[160][36];
  int r0g = nch*128;
  const u16* vb = vv + (long)bh*131072;
  #pragma unroll
  for (int it=0; it<5; it++){
    int slot = tid + it*256;
    int rr = slot>>3, c = (slot&7)*4;
    int s = r0g - 16 + rr;
    ushort4 val; val.x=0; val.y=0; val.z=0; val.w=0;
    if (s>=0 && s<4096) val = *(const ushort4*)(vb + (long)s*32 + c);
    *(ushort4*)&vtile[rr][c] = val;
  }
  __syncthreads();

  f32x4 z4; z4[0]=0.f; z4[1]=0.f; z4[2]=0.f; z4[3]=0.f;
  f32x4 acc[2][2]; f32x4 dacc[2];
  #pragma unroll
  for (int mt=0;mt<2;mt++){ dacc[mt]=z4; acc[mt][0]=z4; acc[mt][1]=z4; }
  const u16* qb  = qq + (long)bh*131072;
  const u16* klb = kl + (long)bh*8192;
  const u16* ub  = uT + (long)bh*8192;
  int r0 = r0g + w*32;
  for (int s=0;s<8;s++){
    s16x8 bk[2];
    #pragma unroll
    for (int nt=0;nt<2;nt++) bk[nt] = *(const s16x8*)(klb + (long)(s*32 + nt*16 + ln)*32 + q*8);
    #pragma unroll
    for (int mt=0;mt<2;mt++){
      s16x8 aq = *(const s16x8*)(qb + (long)(r0 + mt*16 + ln)*32 + q*8);
      #pragma unroll
      for (int nt=0;nt<2;nt++){
        f32x4 sf = MFMA16(aq, bk[nt], z4);
        f32x4 ef;
        #pragma unroll
        for (int r=0;r<4;r++) ef[r] = __expf(sf[r]);
        dacc[mt] += ef;
        #pragma unroll
        for (int r=0;r<4;r++) Pbuf[w][mt*16 + q*4 + r][nt*16 + ln] = f2bf(ef[r]);
      }
    }
    #pragma unroll
    for (int mt=0;mt<2;mt++){
      s16x8 ap = *(const s16x8*)&Pbuf[w][mt*16 + ln][q*8];
      #pragma unroll
      for (int nt=0;nt<2;nt++){
        s16x8 bu = *(const s16x8*)(ub + (long)(nt*16 + ln)*256 + s*32 + q*8);
        acc[mt][nt] = MFMA16(ap, bu, acc[mt][nt]);
      }
    }
  }
  #pragma unroll
  for (int mt=0;mt<2;mt++)
    #pragma unroll
    for (int r=0;r<4;r++){
      float x = dacc[mt][r];
      x += __shfl_xor(x,1); x += __shfl_xor(x,2); x += __shfl_xor(x,4); x += __shfl_xor(x,8);
      dacc[mt][r] = x;
    }

  const float* wp = rw + h*33;
  float w_[33];
  #pragma unroll
  for (int j=0;j<33;j++) w_[j] = wp[j];

  #pragma unroll
  for (int mt=0;mt<2;mt++){
    int nl = w*32 + mt*16 + q*4;
    #pragma unroll
    for (int nt=0;nt<2;nt++){
      int d = nt*16 + ln;
      float vvv[36];
      #pragma unroll
      for (int j=0;j<36;j++) vvv[j] = bf2f(vtile[nl + j][d]);
      #pragma unroll
      for (int r=0;r<4;r++){
        float cv = 0.f;
        #pragma unroll
        for (int j=0;j<33;j++) cv += w_[j]*vvv[r+j];
        int n = r0 + mt*16 + q*4 + r;
        long oidx = ((long)b*4096 + n)*256 + h*32 + d;
        aoutb[oidx] = f2bf(acc[mt][nt][r]/dacc[mt][r] + cv);
      }
    }
  }
}

// ---------------------------------------------------------------------------
// Merged weight transpose+cast (+ zeroes the pinv grid barrier counter)
// ---------------------------------------------------------------------------
__global__ __launch_bounds__(256)
void kcvtall(const float* __restrict__ wqkv, const float* __restrict__ wout,
             const float* __restrict__ w1, const float* __restrict__ w2,
             u16* __restrict__ wqkvT, u16* __restrict__ woutT,
             u16* __restrict__ w1T, u16* __restrict__ w2T,
             unsigned* __restrict__ bar)
{
  __shared__ float t[32][33];
  if (blockIdx.x==0 && threadIdx.x==0) *bar = 0u;
  int z = blockIdx.x;
  const float* src; u16* dst; int K, Nn, bx, by;
  if (z < 384){      int i=z/192, r=z%192; src=wqkv+(long)i*196608; dst=wqkvT+(long)i*196608; K=256; Nn=768; bx=r%24; by=r/24; }
  else if (z < 512){ int zz=z-384; int i=zz/64, r=zz%64; src=wout+(long)i*65536; dst=woutT+(long)i*65536; K=256; Nn=256; bx=r%8; by=r/8; }
  else if (z < 768){ int zz=z-512; int i=zz/128, r=zz%128; src=w1+(long)i*131072; dst=w1T+(long)i*131072; K=256; Nn=512; bx=r%16; by=r/16; }
  else {             int zz=z-768; int i=zz/128, r=zz%128; src=w2+(long)i*131072; dst=w2T+(long)i*131072; K=512; Nn=256; bx=r%8; by=r/8; }
  int n0 = bx*32, k0 = by*32;
  int tx = threadIdx.x&31, ty = threadIdx.x>>5;
  #pragma unroll
  for (int i=0;i<4;i++) t[ty+i*8][tx] = src[(long)(k0+ty+i*8)*Nn + n0+tx];
  __syncthreads();
  #pragma unroll
  for (int i=0;i<4;i++) dst[(long)(n0+ty+i*8)*K + k0+tx] = f2bf(t[tx][ty+i*8]);
}

// ---------------------------------------------------------------------------
extern "C" void kernel_launch(void* const* d_in, const int* in_sizes, int n_in,
                              void* d_out, int out_size, void* d_ws, size_t ws_size,
                              hipStream_t stream)
{
  const float* x    = (const float*)d_in[0];
  const float* ln1g = (const float*)d_in[1];
  const float* ln1b = (const float*)d_in[2];
  const float* wqkv = (const float*)d_in[3];
  const float* wout = (const float*)d_in[4];
  const float* bout = (const float*)d_in[5];
  const float* resw = (const float*)d_in[6];
  const float* ln2g = (const float*)d_in[7];
  const float* ln2b = (const float*)d_in[8];
  const float* w1   = (const float*)d_in[9];
  const float* b1   = (const float*)d_in[10];
  const float* w2   = (const float*)d_in[11];
  const float* b2   = (const float*)d_in[12];
  float* y = (float*)d_out;
  char* ws = (char*)d_ws;

  u16* xn    = (u16*)(ws + 0);
  u16* qb    = (u16*)(ws + 8388608);
  u16* kb    = (u16*)(ws + 16777216);
  u16* vb    = (u16*)(ws + 25165824);
  u16* ql    = (u16*)(ws + 33554432);
  u16* kl    = (u16*)(ws + 34078720);
  u16* X     = (u16*)(ws + 34603008);
  u16* XT    = (u16*)(ws + 38797312);     // doubles as z~0
  u16* w3T   = (u16*)(ws + 42991616);     // [32][64][256] bf16 (rows>=32 zero)
  u16* g1T   = (u16*)(ws + 44040192);     // [32][64][256]
  u16* aT    = (u16*)(ws + 45088768);     // [32][64][256]
  u16* bT    = (u16*)(ws + 46137344);     // [32][64][256]
  // pinv work region: 6 x 4 MB
  u16* WA    = (u16*)(ws + 51380224);
  u16* WB    = (u16*)(ws + 55574528);
  u16* Sb    = (u16*)(ws + 59768832);
  u16* Mb    = (u16*)(ws + 63963136);
  u16* zA    = (u16*)(ws + 68157440);
  u16* zB    = (u16*)(ws + 72351744);
  float* num_p = (float*)(ws + 76546048);  // 8 MB
  float* den_p = (float*)(ws + 84934656);
  float* cs_p  = (float*)(ws + 85196800);
  float* scal  = (float*)(ws + 85458944);
  u16* uT    = (u16*)(ws + 85459200);
  u16* aoutb = (u16*)(ws + 85983488);
  u16* wqkvT = (u16*)(ws + 94372096);
  u16* woutT = (u16*)(ws + 95158528);
  u16* w1T   = (u16*)(ws + 95420672);
  u16* w2T   = (u16*)(ws + 95944960);
  u16* hdn   = (u16*)(ws + 51380224);      // overlays pinv region (dead by FFN)
  unsigned* bar = (unsigned*)(ws + 100663296);

  (void)in_sizes; (void)n_in; (void)out_size; (void)ws_size;

  kcvtall<<<1024,256,0,stream>>>(wqkv, wout, w1, w2, wqkvT, woutT, w1T, w2T, bar);

  for (int i=0;i<2;i++){
    kln<<<4096,256,0,stream>>>(i==0 ? x : y, ln1g + i*256, ln1b + i*256, xn);
    kgemm2<EPI_QKV><<<dim3(128,6),256,0,stream>>>(xn, wqkvT + (long)i*196608, 256, 256, 256,
        nullptr, nullptr, 0, qb,kb,vb, ql,kl);
    kattn23<<<dim3(16,32),256,0,stream>>>(ql, kl, X, XT, cs_p, kb, vb, num_p, den_p);

    // ---- fused: ks0w3 + W0 + 5x(S,M,PAIR) + thin tail, one persistent launch
    kpinv_all<<<512,256,0,stream>>>(cs_p, scal, num_p, den_p, w3T, X, XT,
        WA, WB, Sb, Mb, zA, zB, aT, bT, g1T, uT, bar, (unsigned)(i*20*512));

    kattn1u<<<dim3(32,32),256,0,stream>>>(qb, kl, uT, vb, resw + i*264, aoutb);
    kgemm<EPI_BIAS_RES><<<dim3(128,4),256,0,stream>>>(aoutb, woutT + (long)i*65536, 256,256,256,
        bout + i*256, i==0 ? x : y, y, nullptr, 256);
    kln<<<4096,256,0,stream>>>(y, ln2g + i*256, ln2b + i*256, xn);
    kgemm2<EPI_BIAS_GELU><<<dim3(128,4),256,0,stream>>>(xn, w1T + (long)i*131072, 256, 256, 256,
        b1 + i*512, hdn, 512, nullptr,nullptr,nullptr, nullptr,nullptr);
    kgemm<EPI_BIAS_RES><<<dim3(128,4),256,0,stream>>>(hdn, w2T + (long)i*131072, 512,512,512,
        b2 + i*256, y, y, nullptr, 256);
  }
}

// Round 2
// 610.057 us; speedup vs baseline: 4.5923x; 4.5923x over previous
//
#include <hip/hip_runtime.h>
#include <math.h>

typedef float f32x4 __attribute__((ext_vector_type(4)));
typedef short s16x8 __attribute__((ext_vector_type(8)));
typedef unsigned short u16;
typedef unsigned int u32;

#define MFMA16(a,b,c) __builtin_amdgcn_mfma_f32_16x16x32_bf16((a),(b),(c),0,0,0)
#define AS1 __attribute__((address_space(1)))
#define AS3 __attribute__((address_space(3)))

__device__ __forceinline__ void dma16(const u16* g, u16* l){
  __builtin_amdgcn_global_load_lds((const AS1 u32*)g, (AS3 u32*)l, 16, 0, 0);
}

__device__ __forceinline__ float bf2f(u16 u){
  union { unsigned int i; float f; } v; v.i = ((unsigned int)u)<<16; return v.f;
}
__device__ __forceinline__ u16 f2bf(float f){
  union { float f; unsigned int i; } v; v.f = f;
  unsigned int x = v.i;
  return (u16)((x + 0x7fffu + ((x>>16)&1u))>>16);
}

enum { EPI_QKV=0, EPI_PINV=1, EPI_BIAS_RES=2, EPI_BIAS_GELU=3 };

// ---------------------------------------------------------------------------
// kgemm: BM=128, BN=64, BK=32 (N=256 outputs: RES / RES2).
// ---------------------------------------------------------------------------
template<int EPI>
__global__ __launch_bounds__(256)
void kgemm(const u16* __restrict__ A, const u16* __restrict__ BT, int K, int lda, int ldb,
           const float* __restrict__ bias, const float* __restrict__ base,
           float* __restrict__ resout,
           u16* __restrict__ outb, int ldc)
{
  __shared__ __align__(16) u16 As[128*32];
  __shared__ __align__(16) u16 Bs[64*32];
  const int tid = threadIdx.x;
  const int w = tid>>6, l = tid&63, q = l>>4, ln = l&15;
  const int m0 = blockIdx.x*128, n0 = blockIdx.y*64;
  const int lrow = l>>2, lch = l&3;

  f32x4 acc[2][4];
  #pragma unroll
  for (int i=0;i<2;i++)
    #pragma unroll
    for (int j=0;j<4;j++){ acc[i][j][0]=0.f; acc[i][j][1]=0.f; acc[i][j][2]=0.f; acc[i][j][3]=0.f; }

  for (int k0=0; k0<K; k0+=32){
    #pragma unroll
    for (int c=0;c<2;c++){
      int row = 32*w + 16*c + lrow;
      int gch = lch ^ ((row>>1)&3);
      dma16(A + (long)(m0+row)*lda + k0 + gch*8, &As[(32*w+16*c)*32]);
    }
    {
      int row = 16*w + lrow;
      int gch = lch ^ ((row>>1)&3);
      dma16(BT + (long)(n0+row)*ldb + k0 + gch*8, &Bs[(16*w)*32]);
    }
    __syncthreads();
    s16x8 af[2], bfr[4];
    #pragma unroll
    for (int mt=0;mt<2;mt++){
      int row = w*32 + mt*16 + ln;
      af[mt] = *(const s16x8*)&As[row*32 + ((q ^ ((row>>1)&3))<<3)];
    }
    #pragma unroll
    for (int nt=0;nt<4;nt++){
      int row = nt*16 + ln;
      bfr[nt] = *(const s16x8*)&Bs[row*32 + ((q ^ ((row>>1)&3))<<3)];
    }
    #pragma unroll
    for (int mt=0;mt<2;mt++)
      #pragma unroll
      for (int nt=0;nt<4;nt++)
        acc[mt][nt] = MFMA16(af[mt], bfr[nt], acc[mt][nt]);
    __syncthreads();
  }

  #pragma unroll
  for (int mt=0;mt<2;mt++)
  #pragma unroll
  for (int nt=0;nt<4;nt++)
  #pragma unroll
  for (int r=0;r<4;r++){
    int mrow = m0 + w*32 + mt*16 + q*4 + r;
    int ncol = n0 + nt*16 + ln;
    float v = acc[mt][nt][r];
    if (EPI==EPI_BIAS_RES){
      long idx = (long)mrow*ldc + ncol;
      resout[idx] = base[idx] + v + bias[ncol];
    } else {
      outb[(long)mrow*ldc + ncol] = f2bf(v);
    }
  }
}

// ---------------------------------------------------------------------------
// kgemm2: BM=128, BN=128, BK=32, 4x4 frags/wave; DMA staging + swizzle.
// ---------------------------------------------------------------------------
template<int EPI>
__global__ __launch_bounds__(256)
void kgemm2(const u16* __restrict__ A, const u16* __restrict__ BT, int K, int lda, int ldb,
            const float* __restrict__ bias, u16* __restrict__ outb, int ldc,
            u16* __restrict__ qo, u16* __restrict__ ko, u16* __restrict__ vo,
            u16* __restrict__ qlm, u16* __restrict__ klm)
{
  __shared__ __align__(16) u16 As[128*32];
  __shared__ __align__(16) u16 Bs[128*32];
  const int tid = threadIdx.x;
  const int w = tid>>6, wy = w>>1, wx = w&1, l = tid&63, q = l>>4, ln = l&15;
  const int m0 = blockIdx.x*128, n0 = blockIdx.y*128;
  const int lrow = l>>2, lch = l&3;

  f32x4 acc[4][4];
  #pragma unroll
  for (int i=0;i<4;i++)
    #pragma unroll
    for (int j=0;j<4;j++){ acc[i][j][0]=0.f; acc[i][j][1]=0.f; acc[i][j][2]=0.f; acc[i][j][3]=0.f; }

  for (int k0=0; k0<K; k0+=32){
    #pragma unroll
    for (int c=0;c<2;c++){
      int row = 32*w + 16*c + lrow;
      int gch = lch ^ ((row>>1)&3);
      dma16(A + (long)(m0+row)*lda + k0 + gch*8, &As[(32*w+16*c)*32]);
      dma16(BT + (long)(n0+row)*ldb + k0 + gch*8, &Bs[(32*w+16*c)*32]);
    }
    __syncthreads();
    s16x8 af[4], bfr[4];
    #pragma unroll
    for (int mt=0;mt<4;mt++){
      int row = wy*64 + mt*16 + ln;
      af[mt] = *(const s16x8*)&As[row*32 + ((q ^ ((row>>1)&3))<<3)];
    }
    #pragma unroll
    for (int nt=0;nt<4;nt++){
      int row = wx*64 + nt*16 + ln;
      bfr[nt] = *(const s16x8*)&Bs[row*32 + ((q ^ ((row>>1)&3))<<3)];
    }
    #pragma unroll
    for (int mt=0;mt<4;mt++)
      #pragma unroll
      for (int nt=0;nt<4;nt++)
        acc[mt][nt] = MFMA16(af[mt], bfr[nt], acc[mt][nt]);
    __syncthreads();
  }

  #pragma unroll
  for (int mt=0;mt<4;mt++)
  #pragma unroll
  for (int nt=0;nt<4;nt++){
    int ncol = n0 + wx*64 + nt*16 + ln;
    if (EPI==EPI_QKV){
      int sel = ncol>>8, hd = ncol&255, h = hd>>5, d = hd&31;
      u16* dst = sel==0 ? qo : (sel==1 ? ko : vo);
      float sc2 = (sel==0) ? 0.17677669529663689f : 1.f;   // dh^-0.5 on q
      float s = 0.f;
      #pragma unroll
      for (int r=0;r<4;r++){
        int mrow = m0 + wy*64 + mt*16 + q*4 + r;
        int b = mrow>>12, n = mrow&4095;
        float v = acc[mt][nt][r]*sc2;
        dst[(((long)(b*8+h)*4096 + n)<<5) + d] = f2bf(v);
        s += v;
      }
      if (sel < 2){
        s += __shfl_xor(s, 16);
        s += __shfl_xor(s, 32);
        if (q == 0){
          int mrow0 = m0 + wy*64 + mt*16;
          int b = mrow0>>12, grp = (mrow0&4095)>>4;
          u16* ldst = (sel==0) ? qlm : klm;
          ldst[(((long)(b*8+h)*256 + grp)<<5) + d] = f2bf(s*(1.0f/16.0f));
        }
      }
    } else { // EPI_BIAS_GELU
      #pragma unroll
      for (int r=0;r<4;r++){
        int mrow = m0 + wy*64 + mt*16 + q*4 + r;
        float x = acc[mt][nt][r] + bias[ncol];
        float g = 0.5f*x*(1.0f + erff(x*0.70710678118654752f));
        outb[(long)mrow*ldc + ncol] = f2bf(g);
      }
    }
  }
}

// ---------------------------------------------------------------------------
// Batched pinv GEMM, K=256 staged fully in LDS (64x256 slabs), ONE barrier
// per launch. 64x64 output tiles. Chunk-XOR swizzle on low-3 chunk bits
// (row stride 512B == 0 mod 128B -> same bank geometry as proven 64-col).
//
// Thin-h tracking: all M_k are polynomials of W0 (symmetric, commuting), so
// u = s0*X^T M0..M5 w3 is re-associated right-to-left: h0=w3 [256x64],
// h' = M@h (computed as h^T@M, shares B staging with W'=W@M in PM_WMH).
// ---------------------------------------------------------------------------
enum { PM_W0=0, PM_S=1, PM_M=2, PM_WMH=3, PM_THIN=4, PM_THING=5, PM_U=6 };

template<int MODE>
__global__ __launch_bounds__(256)
void kpinv(const u16* __restrict__ A, const u16* __restrict__ B,
           const u16* __restrict__ A2,
           u16* __restrict__ out, u16* __restrict__ out2,
           const u16* __restrict__ Wp, const u16* __restrict__ Sp,
           const u16* __restrict__ Tp,
           const float* __restrict__ sptr)
{
  __shared__ __align__(16) u16 As[64*256];
  __shared__ __align__(16) u16 Bs[64*256];
  const int tid=threadIdx.x, w=tid>>6, l=tid&63, q=l>>4, ln=l&15;
  const int bz = blockIdx.z;
  const bool hrole = (MODE==PM_WMH) && (blockIdx.y==4);
  const bool thinA = hrole || MODE==PM_THIN || MODE==PM_THING || MODE==PM_U;

  const u16* Ap; int m0, n0;
  if (thinA){
    Ap = (hrole ? A2 : A) + (long)bz*16384;   // [64][256] row-major
    m0 = 0; n0 = blockIdx.x*64;
  } else {
    Ap = A + (long)bz*65536;
    m0 = blockIdx.x*64; n0 = blockIdx.y*64;
  }
  const u16* Bp = B + (long)bz*65536;

  // ---- stage full K=256: 16 dma16/thread issued back-to-back, 1 barrier ----
  const int drow = l>>5, dch = l&31;
  #pragma unroll
  for (int c=0;c<8;c++){
    int rbase = w*16 + c*2;
    int row = rbase + drow;
    int gch = (dch&24) | ((dch&7) ^ ((row>>1)&7));
    dma16(Ap + (long)(m0+row)*256 + gch*8, &As[rbase*256]);
    dma16(Bp + (long)(n0+row)*256 + gch*8, &Bs[rbase*256]);
  }
  __syncthreads();

  f32x4 acc[4];
  #pragma unroll
  for (int j=0;j<4;j++){ acc[j][0]=0.f; acc[j][1]=0.f; acc[j][2]=0.f; acc[j][3]=0.f; }

  const int arow = w*16 + ln;
  #pragma unroll
  for (int kq=0;kq<8;kq++){
    int ca = kq*4 + q;
    s16x8 af = *(const s16x8*)&As[arow*256 + (((ca&24)|((ca&7)^((arow>>1)&7)))<<3)];
    #pragma unroll
    for (int nt=0;nt<4;nt++){
      int brow = nt*16 + ln;
      s16x8 bfr = *(const s16x8*)&Bs[brow*256 + (((ca&24)|((ca&7)^((brow>>1)&7)))<<3)];
      acc[nt] = MFMA16(af, bfr, acc[nt]);
    }
  }

  const float s0 = (MODE==PM_W0 || MODE==PM_U) ? *sptr : 1.f;
  #pragma unroll
  for (int nt=0;nt<4;nt++)
  #pragma unroll
  for (int r=0;r<4;r++){
    int mrow = m0 + w*16 + q*4 + r;
    int ncol = n0 + nt*16 + ln;
    float v = acc[nt][r];
    if (MODE==PM_W0 || MODE==PM_S){
      out[(long)bz*65536 + (long)mrow*256 + ncol] = f2bf(v*s0);
    } else if (MODE==PM_M){
      long idx = (long)bz*65536 + (long)mrow*256 + ncol;
      float wv = bf2f(Wp[idx]), sv = bf2f(Sp[idx]);
      out[idx] = f2bf(0.25f*(((mrow==ncol)?13.f:0.f) - 15.f*wv + 7.f*sv - v));
    } else if (MODE==PM_WMH){
      if (hrole) out2[(long)bz*16384 + (long)mrow*256 + ncol] = f2bf(v);
      else       out [(long)bz*65536 + (long)mrow*256 + ncol] = f2bf(v);
    } else if (MODE==PM_THIN){
      out[(long)bz*16384 + (long)mrow*256 + ncol] = f2bf(v);
    } else if (MODE==PM_THING){
      long idx = (long)bz*16384 + (long)mrow*256 + ncol;
      out[idx] = f2bf(0.25f*(13.f*bf2f(Wp[idx]) - 15.f*bf2f(Sp[idx]) + 7.f*bf2f(Tp[idx]) - v));
    } else { // PM_U: uT[d][m], keep d<32, scale s0
      if (mrow < 32) out[(long)bz*8192 + (long)mrow*256 + ncol] = f2bf(v*s0);
    }
  }
}

// ---------------------------------------------------------------------------
// LayerNorm: one wave per row (256 cols), write bf16
// ---------------------------------------------------------------------------
__global__ __launch_bounds__(256)
void kln(const float* __restrict__ y, const float* __restrict__ g, const float* __restrict__ b,
         u16* __restrict__ out)
{
  int w = threadIdx.x>>6, l = threadIdx.x&63;
  long row = (long)blockIdx.x*4 + w;
  float4 v = ((const float4*)(y + row*256))[l];
  float s = v.x+v.y+v.z+v.w;
  #pragma unroll
  for (int m=1;m<64;m<<=1) s += __shfl_xor(s, m);
  float mu = s*(1.0f/256.0f);
  float dx=v.x-mu, dy=v.y-mu, dz=v.z-mu, dw=v.w-mu;
  float s2 = dx*dx+dy*dy+dz*dz+dw*dw;
  #pragma unroll
  for (int m=1;m<64;m<<=1) s2 += __shfl_xor(s2, m);
  float rs = rsqrtf(s2*(1.0f/256.0f) + 1e-5f);
  float4 gg = ((const float4*)g)[l];
  float4 bb = ((const float4*)b)[l];
  ushort4 o;
  o.x = f2bf(dx*rs*gg.x + bb.x);
  o.y = f2bf(dy*rs*gg.y + bb.y);
  o.z = f2bf(dz*rs*gg.z + bb.z);
  o.w = f2bf(dw*rs*gg.w + bb.w);
  *(ushort4*)(out + row*256 + l*4) = o;
}

// ---------------------------------------------------------------------------
// Merged attn2 + attn3v (independent; grid (16,32): x<8 attn2, x>=8 attn3v)
// ---------------------------------------------------------------------------
__global__ __launch_bounds__(256)
void kattn23(const u16* __restrict__ ql, const u16* __restrict__ kl,
             u16* __restrict__ X, u16* __restrict__ XT, float* __restrict__ cs_p,
             const u16* __restrict__ kk, const u16* __restrict__ vv,
             float* __restrict__ num_p, float* __restrict__ den_p)
{
  __shared__ __align__(16) u16 Pbuf[4][64][40];
  __shared__ __align__(16) u16 vT[32][40];
  __shared__ float qrow[32][33];
  __shared__ float psum[32][4];
  __shared__ float rsum[32];
  int bh = blockIdx.y;
  int tid = threadIdx.x, w = tid>>6, l = tid&63, q = l>>4, ln = l&15;

  if (blockIdx.x < 8){
    int r0 = blockIdx.x*32;
    int c = tid;
    #pragma unroll
    for (int i=0;i<4;i++){
      int e = c*4+i; int rr = e>>5, dd = e&31;
      qrow[rr][dd] = bf2f(ql[((long)bh*256 + r0+rr)*32 + dd]);
    }
    float kc[32];
    {
      const u16* kp = kl + ((long)bh*256 + c)*32;
      #pragma unroll
      for (int d=0;d<32;d++) kc[d] = bf2f(kp[d]);
    }
    __syncthreads();
    float er[32]; float colacc = 0.f;
    for (int r=0;r<32;r++){
      float s = 0.f;
      #pragma unroll
      for (int d=0;d<32;d++) s += qrow[r][d]*kc[d];
      float e = __expf(s);
      er[r] = e;
      float wsum = e;
      #pragma unroll
      for (int m=1;m<64;m<<=1) wsum += __shfl_xor(wsum, m);
      if (l==0) psum[r][w] = wsum;
    }
    __syncthreads();
    if (c<32) rsum[c] = psum[c][0]+psum[c][1]+psum[c][2]+psum[c][3];
    __syncthreads();
    for (int r=0;r<32;r++){
      float x = er[r]/rsum[r];
      u16 xb = f2bf(x);
      X [((long)bh*256 + r0+r)*256 + c] = xb;
      XT[((long)bh*256 + c)*256 + r0+r] = xb;
      colacc += x;
    }
    cs_p[(long)blockIdx.x*8192 + bh*256 + c] = colacc;
    return;
  }

  int chunk = blockIdx.x - 8;
  f32x4 z4; z4[0]=0.f; z4[1]=0.f; z4[2]=0.f; z4[3]=0.f;
  f32x4 acc[4][2]; f32x4 dacc[4];
  #pragma unroll
  for (int mt=0;mt<4;mt++){ dacc[mt]=z4; acc[mt][0]=z4; acc[mt][1]=z4; }
  const u16* qlb = ql + (long)bh*8192;
  const u16* kb  = kk + (long)bh*131072;
  const u16* vb  = vv + (long)bh*131072;
  int vn = tid>>3, vd = (tid&7)*4;
  for (int s=0;s<16;s++){
    int n0 = chunk*512 + s*32;
    ushort4 vx = *(const ushort4*)(vb + (long)(n0+vn)*32 + vd);
    vT[vd+0][vn]=vx.x; vT[vd+1][vn]=vx.y; vT[vd+2][vn]=vx.z; vT[vd+3][vn]=vx.w;
    __syncthreads();
    s16x8 bk[2];
    #pragma unroll
    for (int nt=0;nt<2;nt++) bk[nt] = *(const s16x8*)(kb + (long)(n0 + nt*16 + ln)*32 + q*8);
    #pragma unroll
    for (int mt=0;mt<4;mt++){
      s16x8 aq = *(const s16x8*)(qlb + (long)(w*64 + mt*16 + ln)*32 + q*8);
      #pragma unroll
      for (int nt=0;nt<2;nt++){
        f32x4 sf = MFMA16(aq, bk[nt], z4);
        f32x4 ef;
        #pragma unroll
        for (int r=0;r<4;r++) ef[r] = __expf(sf[r]);
        dacc[mt] += ef;
        #pragma unroll
        for (int r=0;r<4;r++) Pbuf[w][mt*16 + q*4 + r][nt*16 + ln] = f2bf(ef[r]);
      }
    }
    #pragma unroll
    for (int mt=0;mt<4;mt++){
      s16x8 ap = *(const s16x8*)&Pbuf[w][mt*16 + ln][q*8];
      #pragma unroll
      for (int nt=0;nt<2;nt++){
        s16x8 bv = *(const s16x8*)&vT[nt*16 + ln][q*8];
        acc[mt][nt] = MFMA16(ap, bv, acc[mt][nt]);
      }
    }
    __syncthreads();
  }
  #pragma unroll
  for (int mt=0;mt<4;mt++)
    #pragma unroll
    for (int r=0;r<4;r++){
      float x = dacc[mt][r];
      x += __shfl_xor(x,1); x += __shfl_xor(x,2); x += __shfl_xor(x,4); x += __shfl_xor(x,8);
      dacc[mt][r] = x;
    }
  long pbase = (long)(chunk*32 + bh);
  #pragma unroll
  for (int mt=0;mt<4;mt++)
    #pragma unroll
    for (int nt=0;nt<2;nt++)
      #pragma unroll
      for (int r=0;r<4;r++){
        int mg = w*64 + mt*16 + q*4 + r;
        num_p[pbase*8192 + (long)mg*32 + nt*16 + ln] = acc[mt][nt][r];
      }
  if (ln==0){
    #pragma unroll
    for (int mt=0;mt<4;mt++)
      #pragma unroll
      for (int r=0;r<4;r++)
        den_p[pbase*256 + w*64 + mt*16 + q*4 + r] = dacc[mt][r];
  }
}

// ---------------------------------------------------------------------------
// ks0w3: WG0 = 1/max colsum; WG 1+bh = w3T prep (doubles as h0T for pinv)
// ---------------------------------------------------------------------------
__global__ __launch_bounds__(256)
void ks0w3(const float* __restrict__ cs_p, float* __restrict__ scal,
           const float* __restrict__ num_p, const float* __restrict__ den_p,
           u16* __restrict__ w3T)
{
  int t = threadIdx.x;
  if (blockIdx.x == 0){
    __shared__ float red[256];
    float m = 0.f;
    for (int i=t;i<8192;i+=256){
      float s = 0.f;
      #pragma unroll
      for (int c=0;c<8;c++) s += cs_p[(long)c*8192 + i];
      m = fmaxf(m, s);
    }
    red[t] = m; __syncthreads();
    for (int s=128;s>0;s>>=1){ if (t<s) red[t] = fmaxf(red[t], red[t+s]); __syncthreads(); }
    if (t==0) scal[0] = 1.0f/red[0];
    return;
  }
  int bh = blockIdx.x - 1;
  __shared__ float lt[32][257];
  for (int i=t;i<8192;i+=256){
    int m = i>>5, d = i&31;
    float sn = 0.f, sd = 0.f;
    #pragma unroll
    for (int c=0;c<8;c++){
      sn += num_p[((long)(c*32+bh))*8192 + i];
      sd += den_p[(c*32+bh)*256 + m];
    }
    lt[d][m] = sn/sd;
  }
  __syncthreads();
  u16* o = w3T + (long)bh*16384;
  for (int j=t;j<16384;j+=256){
    int d = j>>8, m = j&255;
    o[j] = (d<32) ? f2bf(lt[d][m]) : (u16)0;
  }
}

// ---------------------------------------------------------------------------
// attn1 fused + depthwise residual conv
// ---------------------------------------------------------------------------
__global__ __launch_bounds__(256)
void kattn1u(const u16* __restrict__ qq, const u16* __restrict__ kl, const u16* __restrict__ uT,
             const u16* __restrict__ vv, const float* __restrict__ rw,
             u16* __restrict__ aoutb)
{
  int nch = blockIdx.x, bh = blockIdx.y;
  int b = bh>>3, h = bh&7;
  int tid = threadIdx.x, w = tid>>6, l = tid&63, q = l>>4, ln = l&15;
  __shared__ __align__(16) u16 Pbuf[4][32][40];
  __shared__ __align__(16) u16 vtile[160][36];
  int r0g = nch*128;
  const u16* vb = vv + (long)bh*131072;
  #pragma unroll
  for (int it=0; it<5; it++){
    int slot = tid + it*256;
    int rr = slot>>3, c = (slot&7)*4;
    int s = r0g - 16 + rr;
    ushort4 val; val.x=0; val.y=0; val.z=0; val.w=0;
    if (s>=0 && s<4096) val = *(const ushort4*)(vb + (long)s*32 + c);
    *(ushort4*)&vtile[rr][c] = val;
  }
  __syncthreads();

  f32x4 z4; z4[0]=0.f; z4[1]=0.f; z4[2]=0.f; z4[3]=0.f;
  f32x4 acc[2][2]; f32x4 dacc[2];
  #pragma unroll
  for (int mt=0;mt<2;mt++){ dacc[mt]=z4; acc[mt][0]=z4; acc[mt][1]=z4; }
  const u16* qb  = qq + (long)bh*131072;
  const u16* klb = kl + (long)bh*8192;
  const u16* ub  = uT + (long)bh*8192;
  int r0 = r0g + w*32;
  for (int s=0;s<8;s++){
    s16x8 bk[2];
    #pragma unroll
    for (int nt=0;nt<2;nt++) bk[nt] = *(const s16x8*)(klb + (long)(s*32 + nt*16 + ln)*32 + q*8);
    #pragma unroll
    for (int mt=0;mt<2;mt++){
      s16x8 aq = *(const s16x8*)(qb + (long)(r0 + mt*16 + ln)*32 + q*8);
      #pragma unroll
      for (int nt=0;nt<2;nt++){
        f32x4 sf = MFMA16(aq, bk[nt], z4);
        f32x4 ef;
        #pragma unroll
        for (int r=0;r<4;r++) ef[r] = __expf(sf[r]);
        dacc[mt] += ef;
        #pragma unroll
        for (int r=0;r<4;r++) Pbuf[w][mt*16 + q*4 + r][nt*16 + ln] = f2bf(ef[r]);
      }
    }
    #pragma unroll
    for (int mt=0;mt<2;mt++){
      s16x8 ap = *(const s16x8*)&Pbuf[w][mt*16 + ln][q*8];
      #pragma unroll
      for (int nt=0;nt<2;nt++){
        s16x8 bu = *(const s16x8*)(ub + (long)(nt*16 + ln)*256 + s*32 + q*8);
        acc[mt][nt] = MFMA16(ap, bu, acc[mt][nt]);
      }
    }
  }
  #pragma unroll
  for (int mt=0;mt<2;mt++)
    #pragma unroll
    for (int r=0;r<4;r++){
      float x = dacc[mt][r];
      x += __shfl_xor(x,1); x += __shfl_xor(x,2); x += __shfl_xor(x,4); x += __shfl_xor(x,8);
      dacc[mt][r] = x;
    }

  const float* wp = rw + h*33;
  float w_[33];
  #pragma unroll
  for (int j=0;j<33;j++) w_[j] = wp[j];

  #pragma unroll
  for (int mt=0;mt<2;mt++){
    int nl = w*32 + mt*16 + q*4;
    #pragma unroll
    for (int nt=0;nt<2;nt++){
      int d = nt*16 + ln;
      float vvv[36];
      #pragma unroll
      for (int j=0;j<36;j++) vvv[j] = bf2f(vtile[nl + j][d]);
      #pragma unroll
      for (int r=0;r<4;r++){
        float cv = 0.f;
        #pragma unroll
        for (int j=0;j<33;j++) cv += w_[j]*vvv[r+j];
        int n = r0 + mt*16 + q*4 + r;
        long oidx = ((long)b*4096 + n)*256 + h*32 + d;
        aoutb[oidx] = f2bf(acc[mt][nt][r]/dacc[mt][r] + cv);
      }
    }
  }
}

// ---------------------------------------------------------------------------
// Merged weight transpose+cast: all 4 weights in one launch (grid 1024).
// ---------------------------------------------------------------------------
__global__ __launch_bounds__(256)
void kcvtall(const float* __restrict__ wqkv, const float* __restrict__ wout,
             const float* __restrict__ w1, const float* __restrict__ w2,
             u16* __restrict__ wqkvT, u16* __restrict__ woutT,
             u16* __restrict__ w1T, u16* __restrict__ w2T)
{
  __shared__ float t[32][33];
  int z = blockIdx.x;
  const float* src; u16* dst; int K, Nn, bx, by;
  if (z < 384){      int i=z/192, r=z%192; src=wqkv+(long)i*196608; dst=wqkvT+(long)i*196608; K=256; Nn=768; bx=r%24; by=r/24; }
  else if (z < 512){ int zz=z-384; int i=zz/64, r=zz%64; src=wout+(long)i*65536; dst=woutT+(long)i*65536; K=256; Nn=256; bx=r%8; by=r/8; }
  else if (z < 768){ int zz=z-512; int i=zz/128, r=zz%128; src=w1+(long)i*131072; dst=w1T+(long)i*131072; K=256; Nn=512; bx=r%16; by=r/16; }
  else {             int zz=z-768; int i=zz/128, r=zz%128; src=w2+(long)i*131072; dst=w2T+(long)i*131072; K=512; Nn=256; bx=r%8; by=r/8; }
  int n0 = bx*32, k0 = by*32;
  int tx = threadIdx.x&31, ty = threadIdx.x>>5;
  #pragma unroll
  for (int i=0;i<4;i++) t[ty+i*8][tx] = src[(long)(k0+ty+i*8)*Nn + n0+tx];
  __syncthreads();
  #pragma unroll
  for (int i=0;i<4;i++) dst[(long)(n0+ty+i*8)*K + k0+tx] = f2bf(t[tx][ty+i*8]);
}

// ---------------------------------------------------------------------------
extern "C" void kernel_launch(void* const* d_in, const int* in_sizes, int n_in,
                              void* d_out, int out_size, void* d_ws, size_t ws_size,
                              hipStream_t stream)
{
  const float* x    = (const float*)d_in[0];
  const float* ln1g = (const float*)d_in[1];
  const float* ln1b = (const float*)d_in[2];
  const float* wqkv = (const float*)d_in[3];
  const float* wout = (const float*)d_in[4];
  const float* bout = (const float*)d_in[5];
  const float* resw = (const float*)d_in[6];
  const float* ln2g = (const float*)d_in[7];
  const float* ln2b = (const float*)d_in[8];
  const float* w1   = (const float*)d_in[9];
  const float* b1   = (const float*)d_in[10];
  const float* w2   = (const float*)d_in[11];
  const float* b2   = (const float*)d_in[12];
  float* y = (float*)d_out;
  char* ws = (char*)d_ws;

  u16* xn    = (u16*)(ws + 0);
  u16* qb    = (u16*)(ws + 8388608);
  u16* kb    = (u16*)(ws + 16777216);
  u16* vb    = (u16*)(ws + 25165824);
  u16* ql    = (u16*)(ws + 33554432);
  u16* kl    = (u16*)(ws + 34078720);
  u16* X     = (u16*)(ws + 34603008);
  u16* XT    = (u16*)(ws + 38797312);     // X^T (used by PM_U final GEMM)
  u16* w3T   = (u16*)(ws + 42991616);     // [32][64][256] bf16 (rows>=32 zero) = h0T
  u16* g1T   = (u16*)(ws + 44040192);     // [32][64][256]
  u16* aT    = (u16*)(ws + 45088768);     // [32][64][256]
  u16* bT    = (u16*)(ws + 46137344);     // [32][64][256]
  // pinv work region
  u16* WA    = (u16*)(ws + 51380224);
  u16* WB    = (u16*)(ws + 55574528);
  u16* Sb    = (u16*)(ws + 59768832);
  u16* Mb    = (u16*)(ws + 63963136);
  u16* hA    = (u16*)(ws + 68157440);     // thin h buffers [32][64][256]
  u16* hB    = (u16*)(ws + 72351744);
  float* num_p = (float*)(ws + 76546048);  // 8 MB
  float* den_p = (float*)(ws + 84934656);
  float* cs_p  = (float*)(ws + 85196800);
  float* scal  = (float*)(ws + 85458944);
  u16* uT    = (u16*)(ws + 85459200);
  u16* aoutb = (u16*)(ws + 85983488);
  u16* wqkvT = (u16*)(ws + 94372096);
  u16* woutT = (u16*)(ws + 95158528);
  u16* w1T   = (u16*)(ws + 95420672);
  u16* w2T   = (u16*)(ws + 95944960);
  u16* hdn   = (u16*)(ws + 51380224);      // overlays pinv region (dead by FFN)

  (void)in_sizes; (void)n_in; (void)out_size; (void)ws_size;

  kcvtall<<<1024,256,0,stream>>>(wqkv, wout, w1, w2, wqkvT, woutT, w1T, w2T);

  for (int i=0;i<2;i++){
    kln<<<4096,256,0,stream>>>(i==0 ? x : y, ln1g + i*256, ln1b + i*256, xn);
    kgemm2<EPI_QKV><<<dim3(128,6),256,0,stream>>>(xn, wqkvT + (long)i*196608, 256, 256, 256,
        nullptr, nullptr, 0, qb,kb,vb, ql,kl);
    kattn23<<<dim3(16,32),256,0,stream>>>(ql, kl, X, XT, cs_p, kb, vb, num_p, den_p);
    ks0w3<<<33,256,0,stream>>>(cs_p, scal, num_p, den_p, w3T);

    // ---- pinv: W0, then 5x {S=W^2, M, (W'=W@M | h'=h@M)}, then thin tail ----
    kpinv<PM_W0><<<dim3(4,4,32),256,0,stream>>>(X, X, nullptr, WA, nullptr,
        nullptr, nullptr, nullptr, scal);
    u16 *Wi = WA, *Wo = WB, *hi = w3T, *ho = hA;
    for (int it=0; it<5; it++){
      kpinv<PM_S><<<dim3(4,4,32),256,0,stream>>>(Wi, Wi, nullptr, Sb, nullptr,
          nullptr, nullptr, nullptr, nullptr);
      kpinv<PM_M><<<dim3(4,4,32),256,0,stream>>>(Sb, Wi, nullptr, Mb, nullptr,
          Wi, Sb, nullptr, nullptr);
      kpinv<PM_WMH><<<dim3(4,5,32),256,0,stream>>>(Wi, Mb, hi, Wo, ho,
          nullptr, nullptr, nullptr, nullptr);
      u16* t = Wi; Wi = Wo; Wo = t;
      hi = ho; ho = (ho == hA) ? hB : hA;
    }
    // thin tail: aT=h5T@W5, bT=aT@W5, g1T=.25(13h5-15a+7b-c), uT=s0*g1T@X
    kpinv<PM_THIN><<<dim3(4,1,32),256,0,stream>>>(hi, Wi, nullptr, aT, nullptr,
        nullptr, nullptr, nullptr, nullptr);
    kpinv<PM_THIN><<<dim3(4,1,32),256,0,stream>>>(aT, Wi, nullptr, bT, nullptr,
        nullptr, nullptr, nullptr, nullptr);
    kpinv<PM_THING><<<dim3(4,1,32),256,0,stream>>>(bT, Wi, nullptr, g1T, nullptr,
        hi, aT, bT, nullptr);
    kpinv<PM_U><<<dim3(4,1,32),256,0,stream>>>(g1T, XT, nullptr, uT, nullptr,
        nullptr, nullptr, nullptr, scal);

    kattn1u<<<dim3(32,32),256,0,stream>>>(qb, kl, uT, vb, resw + i*264, aoutb);
    kgemm<EPI_BIAS_RES><<<dim3(128,4),256,0,stream>>>(aoutb, woutT + (long)i*65536, 256,256,256,
        bout + i*256, i==0 ? x : y, y, nullptr, 256);
    kln<<<4096,256,0,stream>>>(y, ln2g + i*256, ln2b + i*256, xn);
    kgemm2<EPI_BIAS_GELU><<<dim3(128,4),256,0,stream>>>(xn, w1T + (long)i*131072, 256, 256, 256,
        b1 + i*512, hdn, 512, nullptr,nullptr,nullptr, nullptr,nullptr);
    kgemm<EPI_BIAS_RES><<<dim3(128,4),256,0,stream>>>(hdn, w2T + (long)i*131072, 512,512,512,
        b2 + i*256, y, y, nullptr, 256);
  }
}

// Round 3
// 542.593 us; speedup vs baseline: 5.1633x; 1.1243x over previous
//
#include <hip/hip_runtime.h>
#include <math.h>

typedef float f32x4 __attribute__((ext_vector_type(4)));
typedef short s16x8 __attribute__((ext_vector_type(8)));
typedef unsigned short u16;
typedef unsigned int u32;

#define MFMA16(a,b,c) __builtin_amdgcn_mfma_f32_16x16x32_bf16((a),(b),(c),0,0,0)
#define AS1 __attribute__((address_space(1)))
#define AS3 __attribute__((address_space(3)))

__device__ __forceinline__ void dma16(const u16* g, u16* l){
  __builtin_amdgcn_global_load_lds((const AS1 u32*)g, (AS3 u32*)l, 16, 0, 0);
}

__device__ __forceinline__ float bf2f(u16 u){
  union { unsigned int i; float f; } v; v.i = ((unsigned int)u)<<16; return v.f;
}
__device__ __forceinline__ u16 f2bf(float f){
  union { float f; unsigned int i; } v; v.f = f;
  unsigned int x = v.i;
  return (u16)((x + 0x7fffu + ((x>>16)&1u))>>16);
}

enum { EPI_QKV=0, EPI_PINV=1, EPI_BIAS_RES=2, EPI_BIAS_GELU=3 };

// ---------------------------------------------------------------------------
// kgemm: BM=128, BN=64, BK=32 (N=256 outputs: RES / RES2).
// ---------------------------------------------------------------------------
template<int EPI>
__global__ __launch_bounds__(256)
void kgemm(const u16* __restrict__ A, const u16* __restrict__ BT, int K, int lda, int ldb,
           const float* __restrict__ bias, const float* __restrict__ base,
           float* __restrict__ resout,
           u16* __restrict__ outb, int ldc)
{
  __shared__ __align__(16) u16 As[128*32];
  __shared__ __align__(16) u16 Bs[64*32];
  const int tid = threadIdx.x;
  const int w = tid>>6, l = tid&63, q = l>>4, ln = l&15;
  const int m0 = blockIdx.x*128, n0 = blockIdx.y*64;
  const int lrow = l>>2, lch = l&3;

  f32x4 acc[2][4];
  #pragma unroll
  for (int i=0;i<2;i++)
    #pragma unroll
    for (int j=0;j<4;j++){ acc[i][j][0]=0.f; acc[i][j][1]=0.f; acc[i][j][2]=0.f; acc[i][j][3]=0.f; }

  for (int k0=0; k0<K; k0+=32){
    #pragma unroll
    for (int c=0;c<2;c++){
      int row = 32*w + 16*c + lrow;
      int gch = lch ^ ((row>>1)&3);
      dma16(A + (long)(m0+row)*lda + k0 + gch*8, &As[(32*w+16*c)*32]);
    }
    {
      int row = 16*w + lrow;
      int gch = lch ^ ((row>>1)&3);
      dma16(BT + (long)(n0+row)*ldb + k0 + gch*8, &Bs[(16*w)*32]);
    }
    __syncthreads();
    s16x8 af[2], bfr[4];
    #pragma unroll
    for (int mt=0;mt<2;mt++){
      int row = w*32 + mt*16 + ln;
      af[mt] = *(const s16x8*)&As[row*32 + ((q ^ ((row>>1)&3))<<3)];
    }
    #pragma unroll
    for (int nt=0;nt<4;nt++){
      int row = nt*16 + ln;
      bfr[nt] = *(const s16x8*)&Bs[row*32 + ((q ^ ((row>>1)&3))<<3)];
    }
    #pragma unroll
    for (int mt=0;mt<2;mt++)
      #pragma unroll
      for (int nt=0;nt<4;nt++)
        acc[mt][nt] = MFMA16(af[mt], bfr[nt], acc[mt][nt]);
    __syncthreads();
  }

  #pragma unroll
  for (int mt=0;mt<2;mt++)
  #pragma unroll
  for (int nt=0;nt<4;nt++)
  #pragma unroll
  for (int r=0;r<4;r++){
    int mrow = m0 + w*32 + mt*16 + q*4 + r;
    int ncol = n0 + nt*16 + ln;
    float v = acc[mt][nt][r];
    if (EPI==EPI_BIAS_RES){
      long idx = (long)mrow*ldc + ncol;
      resout[idx] = base[idx] + v + bias[ncol];
    } else {
      outb[(long)mrow*ldc + ncol] = f2bf(v);
    }
  }
}

// ---------------------------------------------------------------------------
// kgemm2: BM=128, BN=128, BK=32, 4x4 frags/wave; DMA staging + swizzle.
// ---------------------------------------------------------------------------
template<int EPI>
__global__ __launch_bounds__(256)
void kgemm2(const u16* __restrict__ A, const u16* __restrict__ BT, int K, int lda, int ldb,
            const float* __restrict__ bias, u16* __restrict__ outb, int ldc,
            u16* __restrict__ qo, u16* __restrict__ ko, u16* __restrict__ vo,
            u16* __restrict__ qlm, u16* __restrict__ klm)
{
  __shared__ __align__(16) u16 As[128*32];
  __shared__ __align__(16) u16 Bs[128*32];
  const int tid = threadIdx.x;
  const int w = tid>>6, wy = w>>1, wx = w&1, l = tid&63, q = l>>4, ln = l&15;
  const int m0 = blockIdx.x*128, n0 = blockIdx.y*128;
  const int lrow = l>>2, lch = l&3;

  f32x4 acc[4][4];
  #pragma unroll
  for (int i=0;i<4;i++)
    #pragma unroll
    for (int j=0;j<4;j++){ acc[i][j][0]=0.f; acc[i][j][1]=0.f; acc[i][j][2]=0.f; acc[i][j][3]=0.f; }

  for (int k0=0; k0<K; k0+=32){
    #pragma unroll
    for (int c=0;c<2;c++){
      int row = 32*w + 16*c + lrow;
      int gch = lch ^ ((row>>1)&3);
      dma16(A + (long)(m0+row)*lda + k0 + gch*8, &As[(32*w+16*c)*32]);
      dma16(BT + (long)(n0+row)*ldb + k0 + gch*8, &Bs[(32*w+16*c)*32]);
    }
    __syncthreads();
    s16x8 af[4], bfr[4];
    #pragma unroll
    for (int mt=0;mt<4;mt++){
      int row = wy*64 + mt*16 + ln;
      af[mt] = *(const s16x8*)&As[row*32 + ((q ^ ((row>>1)&3))<<3)];
    }
    #pragma unroll
    for (int nt=0;nt<4;nt++){
      int row = wx*64 + nt*16 + ln;
      bfr[nt] = *(const s16x8*)&Bs[row*32 + ((q ^ ((row>>1)&3))<<3)];
    }
    #pragma unroll
    for (int mt=0;mt<4;mt++)
      #pragma unroll
      for (int nt=0;nt<4;nt++)
        acc[mt][nt] = MFMA16(af[mt], bfr[nt], acc[mt][nt]);
    __syncthreads();
  }

  #pragma unroll
  for (int mt=0;mt<4;mt++)
  #pragma unroll
  for (int nt=0;nt<4;nt++){
    int ncol = n0 + wx*64 + nt*16 + ln;
    if (EPI==EPI_QKV){
      int sel = ncol>>8, hd = ncol&255, h = hd>>5, d = hd&31;
      u16* dst = sel==0 ? qo : (sel==1 ? ko : vo);
      float sc2 = (sel==0) ? 0.17677669529663689f : 1.f;   // dh^-0.5 on q
      float s = 0.f;
      #pragma unroll
      for (int r=0;r<4;r++){
        int mrow = m0 + wy*64 + mt*16 + q*4 + r;
        int b = mrow>>12, n = mrow&4095;
        float v = acc[mt][nt][r]*sc2;
        dst[(((long)(b*8+h)*4096 + n)<<5) + d] = f2bf(v);
        s += v;
      }
      if (sel < 2){
        s += __shfl_xor(s, 16);
        s += __shfl_xor(s, 32);
        if (q == 0){
          int mrow0 = m0 + wy*64 + mt*16;
          int b = mrow0>>12, grp = (mrow0&4095)>>4;
          u16* ldst = (sel==0) ? qlm : klm;
          ldst[(((long)(b*8+h)*256 + grp)<<5) + d] = f2bf(s*(1.0f/16.0f));
        }
      }
    } else { // EPI_BIAS_GELU
      #pragma unroll
      for (int r=0;r<4;r++){
        int mrow = m0 + wy*64 + mt*16 + q*4 + r;
        float x = acc[mt][nt][r] + bias[ncol];
        float g = 0.5f*x*(1.0f + erff(x*0.70710678118654752f));
        outb[(long)mrow*ldc + ncol] = f2bf(g);
      }
    }
  }
}

// ---------------------------------------------------------------------------
// Fused pinv: full 256x256 W resident in LDS (128 KB) + 16 KB t-slab.
// W' = 0.25(13W -15W^2 +7W^3 -W^4) per 32-row slab via 3 chained slab@W
// multiplies (no S/M materialization). h'^T = 0.25(13h -15hW +7hW^2 -hW^3).
// One launch per Newton iteration. LDS 144 KB -> 1 block/CU, 256 blocks.
// ---------------------------------------------------------------------------
__device__ __forceinline__ int swidx(int row, int col){
  int cc = col>>3;
  int sl = (cc&24)|((cc&7)^((row>>1)&7));
  return row*256 + sl*8 + (col&7);
}

// stage 256x256 bf16 (131072B), rows swizzled by chunk-XOR (pre-swizzled src)
__device__ __forceinline__ void stage256(const u16* __restrict__ g, u16* lds, int w, int l){
  const int drow = l>>5, dch = l&31;
  #pragma unroll
  for (int c=0;c<32;c++){
    int base = (c*4 + w)*2;
    int row = base + drow;
    int gch = (dch&24) | ((dch&7) ^ ((row>>1)&7));
    dma16(g + (long)row*256 + gch*8, &lds[base*256]);
  }
}

// stage 32x256 bf16 (16KB) slab
__device__ __forceinline__ void stage32(const u16* __restrict__ g, u16* lds, int w, int l){
  const int drow = l>>5, dch = l&31;
  #pragma unroll
  for (int c=0;c<4;c++){
    int base = (c*4 + w)*2;
    int row = base + drow;
    int gch = (dch&24) | ((dch&7) ^ ((row>>1)&7));
    dma16(g + (long)row*256 + gch*8, &lds[base*256]);
  }
}

// t[32x256] = A(rows arow0..arow0+31 of aL) @ B^T-form (bL rows), K=256
__device__ __forceinline__ void mult32(const u16* aL, int arow0, const u16* bL,
                                       int w, int l, f32x4 (&acc)[2][4]){
  const int q=l>>4, ln=l&15, wn0=w*64;
  #pragma unroll
  for (int mt=0;mt<2;mt++)
    #pragma unroll
    for (int nt=0;nt<4;nt++){ acc[mt][nt][0]=0.f; acc[mt][nt][1]=0.f; acc[mt][nt][2]=0.f; acc[mt][nt][3]=0.f; }
  #pragma unroll
  for (int kq=0;kq<8;kq++){
    int ca = kq*4+q;
    s16x8 af[2];
    #pragma unroll
    for (int mt=0;mt<2;mt++){
      int r = arow0 + mt*16 + ln;
      af[mt] = *(const s16x8*)&aL[r*256 + (((ca&24)|((ca&7)^((r>>1)&7)))<<3)];
    }
    #pragma unroll
    for (int nt=0;nt<4;nt++){
      int n = wn0 + nt*16 + ln;
      s16x8 bfr = *(const s16x8*)&bL[n*256 + (((ca&24)|((ca&7)^((n>>1)&7)))<<3)];
      acc[0][nt] = MFMA16(af[0], bfr, acc[0][nt]);
      acc[1][nt] = MFMA16(af[1], bfr, acc[1][nt]);
    }
  }
}

__device__ __forceinline__ void polyinit13(const u16* aL, int arow0, int w, int l, f32x4 (&poly)[2][4]){
  const int q=l>>4, ln=l&15, wn0=w*64;
  #pragma unroll
  for (int mt=0;mt<2;mt++)
  #pragma unroll
  for (int nt=0;nt<4;nt++)
  #pragma unroll
  for (int r=0;r<4;r++){
    int row = arow0 + mt*16 + q*4 + r;
    int col = wn0 + nt*16 + ln;
    poly[mt][nt][r] = 13.f*bf2f(aL[swidx(row,col)]);
  }
}

__device__ __forceinline__ void polyaxpy(f32x4 (&poly)[2][4], const f32x4 (&acc)[2][4], float sc){
  #pragma unroll
  for (int mt=0;mt<2;mt++)
    #pragma unroll
    for (int nt=0;nt<4;nt++)
      #pragma unroll
      for (int r=0;r<4;r++) poly[mt][nt][r] += sc*acc[mt][nt][r];
}

__device__ __forceinline__ void writeT(u16* Ts, const f32x4 (&acc)[2][4], int w, int l, float sc){
  const int q=l>>4, ln=l&15, wn0=w*64;
  #pragma unroll
  for (int mt=0;mt<2;mt++)
  #pragma unroll
  for (int nt=0;nt<4;nt++)
  #pragma unroll
  for (int r=0;r<4;r++){
    int row = mt*16 + q*4 + r;
    int col = wn0 + nt*16 + ln;
    Ts[swidx(row,col)] = f2bf(sc*acc[mt][nt][r]);
  }
}

__device__ __forceinline__ void epi_poly(u16* __restrict__ out, int rowbase,
                                         const f32x4 (&poly)[2][4], int w, int l, float sc){
  const int q=l>>4, ln=l&15, wn0=w*64;
  #pragma unroll
  for (int mt=0;mt<2;mt++)
  #pragma unroll
  for (int nt=0;nt<4;nt++)
  #pragma unroll
  for (int r=0;r<4;r++){
    int row = rowbase + mt*16 + q*4 + r;
    int col = wn0 + nt*16 + ln;
    out[(long)row*256 + col] = f2bf(sc*poly[mt][nt][r]);
  }
}

// kw0: W0 = s0*X@X^T slab; self-computed s0 from cs_p; slab0 also preps h0
__global__ __launch_bounds__(256)
void kw0(const float* __restrict__ cs_p, float* __restrict__ scal,
         const float* __restrict__ num_p, const float* __restrict__ den_p,
         const u16* __restrict__ X, u16* __restrict__ W0, u16* __restrict__ h0)
{
  __shared__ __align__(16) u16 Wf[65536];
  __shared__ __align__(16) u16 Ts[8192];
  const int tid=threadIdx.x, w=tid>>6, l=tid&63;
  const int bid=blockIdx.x, xcd=bid&7, j=bid>>3;
  const int batch = xcd*4 + (j>>3), slab = j&7;

  stage256(X + (long)batch*65536, Wf, w, l);   // dma in flight during reduce

  float* red = (float*)Ts;
  float mx = 0.f;
  for (int i=tid;i<8192;i+=256){
    float s = 0.f;
    #pragma unroll
    for (int c=0;c<8;c++) s += cs_p[(long)c*8192 + i];
    mx = fmaxf(mx, s);
  }
  red[tid] = mx; __syncthreads();
  for (int s=128;s>0;s>>=1){ if (tid<s) red[tid] = fmaxf(red[tid], red[tid+s]); __syncthreads(); }
  float s0 = 1.0f/red[0];
  if (bid==0 && tid==0) scal[0] = s0;

  f32x4 acc[2][4];
  mult32(Wf, slab*32, Wf, w, l, acc);
  {
    const int q=l>>4, ln=l&15, wn0=w*64;
    u16* ob = W0 + (long)batch*65536;
    #pragma unroll
    for (int mt=0;mt<2;mt++)
    #pragma unroll
    for (int nt=0;nt<4;nt++)
    #pragma unroll
    for (int r=0;r<4;r++){
      int row = slab*32 + mt*16 + q*4 + r;
      int col = wn0 + nt*16 + ln;
      ob[(long)row*256 + col] = f2bf(acc[mt][nt][r]*s0);
    }
  }

  if (slab==0){
    __syncthreads();
    float (*lt)[257] = (float(*)[257])Wf;
    for (int i=tid;i<8192;i+=256){
      int m = i>>5, d = i&31;
      float sn = 0.f, sd = 0.f;
      #pragma unroll
      for (int c=0;c<8;c++){
        sn += num_p[((long)(c*32+batch))*8192 + i];
        sd += den_p[(c*32+batch)*256 + m];
      }
      lt[d][m] = sn/sd;
    }
    __syncthreads();
    u16* o = h0 + (long)batch*8192;
    for (int j2=tid;j2<8192;j2+=256){
      int d = j2>>8, m = j2&255;
      o[j2] = f2bf(lt[d][m]);
    }
  }
}

// kiter: one Newton iteration. 256 blocks = 32 batches x 8 slabs; slab0 also h.
__global__ __launch_bounds__(256)
void kiter(const u16* __restrict__ Win, u16* __restrict__ Wout,
           const u16* __restrict__ hin, u16* __restrict__ hout)
{
  __shared__ __align__(16) u16 Wf[65536];
  __shared__ __align__(16) u16 Ts[8192];
  const int tid=threadIdx.x, w=tid>>6, l=tid&63;
  const int bid=blockIdx.x, xcd=bid&7, j=bid>>3;
  const int batch = xcd*4 + (j>>3), slab = j&7;

  stage256(Win + (long)batch*65536, Wf, w, l);
  __syncthreads();

  f32x4 acc[2][4], poly[2][4];
  polyinit13(Wf, slab*32, w, l, poly);
  mult32(Wf, slab*32, Wf, w, l, acc);          // t1 = Wslab@W
  polyaxpy(poly, acc, -15.f);
  writeT(Ts, acc, w, l, 1.f);                  // Ts was free
  __syncthreads();
  mult32(Ts, 0, Wf, w, l, acc);                // t2
  polyaxpy(poly, acc, 7.f);
  __syncthreads();
  writeT(Ts, acc, w, l, 1.f);
  __syncthreads();
  mult32(Ts, 0, Wf, w, l, acc);                // t3
  polyaxpy(poly, acc, -1.f);
  epi_poly(Wout + (long)batch*65536, slab*32, poly, w, l, 0.25f);

  if (slab==0){
    __syncthreads();                            // all waves past Ts(t2) reads
    stage32(hin + (long)batch*8192, Ts, w, l);
    __syncthreads();
    polyinit13(Ts, 0, w, l, poly);
    mult32(Ts, 0, Wf, w, l, acc);               // h@W
    polyaxpy(poly, acc, -15.f);
    __syncthreads(); writeT(Ts, acc, w, l, 1.f); __syncthreads();
    mult32(Ts, 0, Wf, w, l, acc);               // h@W^2
    polyaxpy(poly, acc, 7.f);
    __syncthreads(); writeT(Ts, acc, w, l, 1.f); __syncthreads();
    mult32(Ts, 0, Wf, w, l, acc);               // h@W^3
    polyaxpy(poly, acc, -1.f);
    epi_poly(hout + (long)batch*8192, 0, poly, w, l, 0.25f);
  }
}

// ktail: g1 = 0.25(13h5 -15 h5W -... chain) in-LDS, then u = s0*g1@X (via XT)
__global__ __launch_bounds__(256)
void ktail(const u16* __restrict__ W5, const u16* __restrict__ h5,
           const u16* __restrict__ XT, const float* __restrict__ scal,
           u16* __restrict__ uT)
{
  __shared__ __align__(16) u16 Wf[65536];
  __shared__ __align__(16) u16 Ts[8192];
  const int tid=threadIdx.x, w=tid>>6, l=tid&63;
  const int batch = blockIdx.x;

  stage256(W5 + (long)batch*65536, Wf, w, l);
  stage32(h5 + (long)batch*8192, Ts, w, l);
  __syncthreads();

  f32x4 acc[2][4], poly[2][4];
  polyinit13(Ts, 0, w, l, poly);
  mult32(Ts, 0, Wf, w, l, acc);                 // a = h5@W5
  polyaxpy(poly, acc, -15.f);
  __syncthreads(); writeT(Ts, acc, w, l, 1.f); __syncthreads();
  mult32(Ts, 0, Wf, w, l, acc);                 // b
  polyaxpy(poly, acc, 7.f);
  __syncthreads(); writeT(Ts, acc, w, l, 1.f); __syncthreads();
  mult32(Ts, 0, Wf, w, l, acc);                 // c
  polyaxpy(poly, acc, -1.f);
  __syncthreads();
  writeT(Ts, poly, w, l, 0.25f);                // g1 -> Ts
  __syncthreads();
  stage256(XT + (long)batch*65536, Wf, w, l);   // X^T over W5
  __syncthreads();
  mult32(Ts, 0, Wf, w, l, acc);                 // u = g1@X
  const float s0 = scal[0];
  {
    const int q=l>>4, ln=l&15, wn0=w*64;
    u16* ob = uT + (long)batch*8192;
    #pragma unroll
    for (int mt=0;mt<2;mt++)
    #pragma unroll
    for (int nt=0;nt<4;nt++)
    #pragma unroll
    for (int r=0;r<4;r++){
      int row = mt*16 + q*4 + r;
      int col = wn0 + nt*16 + ln;
      ob[(long)row*256 + col] = f2bf(acc[mt][nt][r]*s0);
    }
  }
}

// ---------------------------------------------------------------------------
// LayerNorm: one wave per row (256 cols), write bf16
// ---------------------------------------------------------------------------
__global__ __launch_bounds__(256)
void kln(const float* __restrict__ y, const float* __restrict__ g, const float* __restrict__ b,
         u16* __restrict__ out)
{
  int w = threadIdx.x>>6, l = threadIdx.x&63;
  long row = (long)blockIdx.x*4 + w;
  float4 v = ((const float4*)(y + row*256))[l];
  float s = v.x+v.y+v.z+v.w;
  #pragma unroll
  for (int m=1;m<64;m<<=1) s += __shfl_xor(s, m);
  float mu = s*(1.0f/256.0f);
  float dx=v.x-mu, dy=v.y-mu, dz=v.z-mu, dw=v.w-mu;
  float s2 = dx*dx+dy*dy+dz*dz+dw*dw;
  #pragma unroll
  for (int m=1;m<64;m<<=1) s2 += __shfl_xor(s2, m);
  float rs = rsqrtf(s2*(1.0f/256.0f) + 1e-5f);
  float4 gg = ((const float4*)g)[l];
  float4 bb = ((const float4*)b)[l];
  ushort4 o;
  o.x = f2bf(dx*rs*gg.x + bb.x);
  o.y = f2bf(dy*rs*gg.y + bb.y);
  o.z = f2bf(dz*rs*gg.z + bb.z);
  o.w = f2bf(dw*rs*gg.w + bb.w);
  *(ushort4*)(out + row*256 + l*4) = o;
}

// ---------------------------------------------------------------------------
// Merged attn2 + attn3v (independent; grid (16,32): x<8 attn2, x>=8 attn3v)
// ---------------------------------------------------------------------------
__global__ __launch_bounds__(256)
void kattn23(const u16* __restrict__ ql, const u16* __restrict__ kl,
             u16* __restrict__ X, u16* __restrict__ XT, float* __restrict__ cs_p,
             const u16* __restrict__ kk, const u16* __restrict__ vv,
             float* __restrict__ num_p, float* __restrict__ den_p)
{
  __shared__ __align__(16) u16 Pbuf[4][64][40];
  __shared__ __align__(16) u16 vT[32][40];
  __shared__ float qrow[32][33];
  __shared__ float psum[32][4];
  __shared__ float rsum[32];
  int bh = blockIdx.y;
  int tid = threadIdx.x, w = tid>>6, l = tid&63, q = l>>4, ln = l&15;

  if (blockIdx.x < 8){
    int r0 = blockIdx.x*32;
    int c = tid;
    #pragma unroll
    for (int i=0;i<4;i++){
      int e = c*4+i; int rr = e>>5, dd = e&31;
      qrow[rr][dd] = bf2f(ql[((long)bh*256 + r0+rr)*32 + dd]);
    }
    float kc[32];
    {
      const u16* kp = kl + ((long)bh*256 + c)*32;
      #pragma unroll
      for (int d=0;d<32;d++) kc[d] = bf2f(kp[d]);
    }
    __syncthreads();
    float er[32]; float colacc = 0.f;
    for (int r=0;r<32;r++){
      float s = 0.f;
      #pragma unroll
      for (int d=0;d<32;d++) s += qrow[r][d]*kc[d];
      float e = __expf(s);
      er[r] = e;
      float wsum = e;
      #pragma unroll
      for (int m=1;m<64;m<<=1) wsum += __shfl_xor(wsum, m);
      if (l==0) psum[r][w] = wsum;
    }
    __syncthreads();
    if (c<32) rsum[c] = psum[c][0]+psum[c][1]+psum[c][2]+psum[c][3];
    __syncthreads();
    for (int r=0;r<32;r++){
      float x = er[r]/rsum[r];
      u16 xb = f2bf(x);
      X [((long)bh*256 + r0+r)*256 + c] = xb;
      XT[((long)bh*256 + c)*256 + r0+r] = xb;
      colacc += x;
    }
    cs_p[(long)blockIdx.x*8192 + bh*256 + c] = colacc;
    return;
  }

  int chunk = blockIdx.x - 8;
  f32x4 z4; z4[0]=0.f; z4[1]=0.f; z4[2]=0.f; z4[3]=0.f;
  f32x4 acc[4][2]; f32x4 dacc[4];
  #pragma unroll
  for (int mt=0;mt<4;mt++){ dacc[mt]=z4; acc[mt][0]=z4; acc[mt][1]=z4; }
  const u16* qlb = ql + (long)bh*8192;
  const u16* kb  = kk + (long)bh*131072;
  const u16* vb  = vv + (long)bh*131072;
  int vn = tid>>3, vd = (tid&7)*4;
  for (int s=0;s<16;s++){
    int n0 = chunk*512 + s*32;
    ushort4 vx = *(const ushort4*)(vb + (long)(n0+vn)*32 + vd);
    vT[vd+0][vn]=vx.x; vT[vd+1][vn]=vx.y; vT[vd+2][vn]=vx.z; vT[vd+3][vn]=vx.w;
    __syncthreads();
    s16x8 bk[2];
    #pragma unroll
    for (int nt=0;nt<2;nt++) bk[nt] = *(const s16x8*)(kb + (long)(n0 + nt*16 + ln)*32 + q*8);
    #pragma unroll
    for (int mt=0;mt<4;mt++){
      s16x8 aq = *(const s16x8*)(qlb + (long)(w*64 + mt*16 + ln)*32 + q*8);
      #pragma unroll
      for (int nt=0;nt<2;nt++){
        f32x4 sf = MFMA16(aq, bk[nt], z4);
        f32x4 ef;
        #pragma unroll
        for (int r=0;r<4;r++) ef[r] = __expf(sf[r]);
        dacc[mt] += ef;
        #pragma unroll
        for (int r=0;r<4;r++) Pbuf[w][mt*16 + q*4 + r][nt*16 + ln] = f2bf(ef[r]);
      }
    }
    #pragma unroll
    for (int mt=0;mt<4;mt++){
      s16x8 ap = *(const s16x8*)&Pbuf[w][mt*16 + ln][q*8];
      #pragma unroll
      for (int nt=0;nt<2;nt++){
        s16x8 bv = *(const s16x8*)&vT[nt*16 + ln][q*8];
        acc[mt][nt] = MFMA16(ap, bv, acc[mt][nt]);
      }
    }
    __syncthreads();
  }
  #pragma unroll
  for (int mt=0;mt<4;mt++)
    #pragma unroll
    for (int r=0;r<4;r++){
      float x = dacc[mt][r];
      x += __shfl_xor(x,1); x += __shfl_xor(x,2); x += __shfl_xor(x,4); x += __shfl_xor(x,8);
      dacc[mt][r] = x;
    }
  long pbase = (long)(chunk*32 + bh);
  #pragma unroll
  for (int mt=0;mt<4;mt++)
    #pragma unroll
    for (int nt=0;nt<2;nt++)
      #pragma unroll
      for (int r=0;r<4;r++){
        int mg = w*64 + mt*16 + q*4 + r;
        num_p[pbase*8192 + (long)mg*32 + nt*16 + ln] = acc[mt][nt][r];
      }
  if (ln==0){
    #pragma unroll
    for (int mt=0;mt<4;mt++)
      #pragma unroll
      for (int r=0;r<4;r++)
        den_p[pbase*256 + w*64 + mt*16 + q*4 + r] = dacc[mt][r];
  }
}

// ---------------------------------------------------------------------------
// attn1 fused + depthwise residual conv
// ---------------------------------------------------------------------------
__global__ __launch_bounds__(256)
void kattn1u(const u16* __restrict__ qq, const u16* __restrict__ kl, const u16* __restrict__ uT,
             const u16* __restrict__ vv, const float* __restrict__ rw,
             u16* __restrict__ aoutb)
{
  int nch = blockIdx.x, bh = blockIdx.y;
  int b = bh>>3, h = bh&7;
  int tid = threadIdx.x, w = tid>>6, l = tid&63, q = l>>4, ln = l&15;
  __shared__ __align__(16) u16 Pbuf[4][32][40];
  __shared__ __align__(16) u16 vtile[160][36];
  int r0g = nch*128;
  const u16* vb = vv + (long)bh*131072;
  #pragma unroll
  for (int it=0; it<5; it++){
    int slot = tid + it*256;
    int rr = slot>>3, c = (slot&7)*4;
    int s = r0g - 16 + rr;
    ushort4 val; val.x=0; val.y=0; val.z=0; val.w=0;
    if (s>=0 && s<4096) val = *(const ushort4*)(vb + (long)s*32 + c);
    *(ushort4*)&vtile[rr][c] = val;
  }
  __syncthreads();

  f32x4 z4; z4[0]=0.f; z4[1]=0.f; z4[2]=0.f; z4[3]=0.f;
  f32x4 acc[2][2]; f32x4 dacc[2];
  #pragma unroll
  for (int mt=0;mt<2;mt++){ dacc[mt]=z4; acc[mt][0]=z4; acc[mt][1]=z4; }
  const u16* qb  = qq + (long)bh*131072;
  const u16* klb = kl + (long)bh*8192;
  const u16* ub  = uT + (long)bh*8192;
  int r0 = r0g + w*32;
  for (int s=0;s<8;s++){
    s16x8 bk[2];
    #pragma unroll
    for (int nt=0;nt<2;nt++) bk[nt] = *(const s16x8*)(klb + (long)(s*32 + nt*16 + ln)*32 + q*8);
    #pragma unroll
    for (int mt=0;mt<2;mt++){
      s16x8 aq = *(const s16x8*)(qb + (long)(r0 + mt*16 + ln)*32 + q*8);
      #pragma unroll
      for (int nt=0;nt<2;nt++){
        f32x4 sf = MFMA16(aq, bk[nt], z4);
        f32x4 ef;
        #pragma unroll
        for (int r=0;r<4;r++) ef[r] = __expf(sf[r]);
        dacc[mt] += ef;
        #pragma unroll
        for (int r=0;r<4;r++) Pbuf[w][mt*16 + q*4 + r][nt*16 + ln] = f2bf(ef[r]);
      }
    }
    #pragma unroll
    for (int mt=0;mt<2;mt++){
      s16x8 ap = *(const s16x8*)&Pbuf[w][mt*16 + ln][q*8];
      #pragma unroll
      for (int nt=0;nt<2;nt++){
        s16x8 bu = *(const s16x8*)(ub + (long)(nt*16 + ln)*256 + s*32 + q*8);
        acc[mt][nt] = MFMA16(ap, bu, acc[mt][nt]);
      }
    }
  }
  #pragma unroll
  for (int mt=0;mt<2;mt++)
    #pragma unroll
    for (int r=0;r<4;r++){
      float x = dacc[mt][r];
      x += __shfl_xor(x,1); x += __shfl_xor(x,2); x += __shfl_xor(x,4); x += __shfl_xor(x,8);
      dacc[mt][r] = x;
    }

  const float* wp = rw + h*33;
  float w_[33];
  #pragma unroll
  for (int j=0;j<33;j++) w_[j] = wp[j];

  #pragma unroll
  for (int mt=0;mt<2;mt++){
    int nl = w*32 + mt*16 + q*4;
    #pragma unroll
    for (int nt=0;nt<2;nt++){
      int d = nt*16 + ln;
      float vvv[36];
      #pragma unroll
      for (int j=0;j<36;j++) vvv[j] = bf2f(vtile[nl + j][d]);
      #pragma unroll
      for (int r=0;r<4;r++){
        float cv = 0.f;
        #pragma unroll
        for (int j=0;j<33;j++) cv += w_[j]*vvv[r+j];
        int n = r0 + mt*16 + q*4 + r;
        long oidx = ((long)b*4096 + n)*256 + h*32 + d;
        aoutb[oidx] = f2bf(acc[mt][nt][r]/dacc[mt][r] + cv);
      }
    }
  }
}

// ---------------------------------------------------------------------------
// Merged weight transpose+cast: all 4 weights in one launch (grid 1024).
// ---------------------------------------------------------------------------
__global__ __launch_bounds__(256)
void kcvtall(const float* __restrict__ wqkv, const float* __restrict__ wout,
             const float* __restrict__ w1, const float* __restrict__ w2,
             u16* __restrict__ wqkvT, u16* __restrict__ woutT,
             u16* __restrict__ w1T, u16* __restrict__ w2T)
{
  __shared__ float t[32][33];
  int z = blockIdx.x;
  const float* src; u16* dst; int K, Nn, bx, by;
  if (z < 384){      int i=z/192, r=z%192; src=wqkv+(long)i*196608; dst=wqkvT+(long)i*196608; K=256; Nn=768; bx=r%24; by=r/24; }
  else if (z < 512){ int zz=z-384; int i=zz/64, r=zz%64; src=wout+(long)i*65536; dst=woutT+(long)i*65536; K=256; Nn=256; bx=r%8; by=r/8; }
  else if (z < 768){ int zz=z-512; int i=zz/128, r=zz%128; src=w1+(long)i*131072; dst=w1T+(long)i*131072; K=256; Nn=512; bx=r%16; by=r/16; }
  else {             int zz=z-768; int i=zz/128, r=zz%128; src=w2+(long)i*131072; dst=w2T+(long)i*131072; K=512; Nn=256; bx=r%8; by=r/8; }
  int n0 = bx*32, k0 = by*32;
  int tx = threadIdx.x&31, ty = threadIdx.x>>5;
  #pragma unroll
  for (int i=0;i<4;i++) t[ty+i*8][tx] = src[(long)(k0+ty+i*8)*Nn + n0+tx];
  __syncthreads();
  #pragma unroll
  for (int i=0;i<4;i++) dst[(long)(n0+ty+i*8)*K + k0+tx] = f2bf(t[tx][ty+i*8]);
}

// ---------------------------------------------------------------------------
extern "C" void kernel_launch(void* const* d_in, const int* in_sizes, int n_in,
                              void* d_out, int out_size, void* d_ws, size_t ws_size,
                              hipStream_t stream)
{
  const float* x    = (const float*)d_in[0];
  const float* ln1g = (const float*)d_in[1];
  const float* ln1b = (const float*)d_in[2];
  const float* wqkv = (const float*)d_in[3];
  const float* wout = (const float*)d_in[4];
  const float* bout = (const float*)d_in[5];
  const float* resw = (const float*)d_in[6];
  const float* ln2g = (const float*)d_in[7];
  const float* ln2b = (const float*)d_in[8];
  const float* w1   = (const float*)d_in[9];
  const float* b1   = (const float*)d_in[10];
  const float* w2   = (const float*)d_in[11];
  const float* b2   = (const float*)d_in[12];
  float* y = (float*)d_out;
  char* ws = (char*)d_ws;

  u16* xn    = (u16*)(ws + 0);
  u16* qb    = (u16*)(ws + 8388608);
  u16* kb    = (u16*)(ws + 16777216);
  u16* vb    = (u16*)(ws + 25165824);
  u16* ql    = (u16*)(ws + 33554432);
  u16* kl    = (u16*)(ws + 34078720);
  u16* X     = (u16*)(ws + 34603008);
  u16* XT    = (u16*)(ws + 38797312);     // X^T (B-operand of final U GEMM)
  u16* h0b   = (u16*)(ws + 42991616);     // h0 [32][32][256] bf16 (512 KB)
  // pinv work region
  u16* WA    = (u16*)(ws + 51380224);
  u16* WB    = (u16*)(ws + 55574528);
  u16* hA    = (u16*)(ws + 68157440);     // thin h buffers [32][32][256]
  u16* hB    = (u16*)(ws + 72351744);
  float* num_p = (float*)(ws + 76546048);  // 8 MB
  float* den_p = (float*)(ws + 84934656);
  float* cs_p  = (float*)(ws + 85196800);
  float* scal  = (float*)(ws + 85458944);
  u16* uT    = (u16*)(ws + 85459200);
  u16* aoutb = (u16*)(ws + 85983488);
  u16* wqkvT = (u16*)(ws + 94372096);
  u16* woutT = (u16*)(ws + 95158528);
  u16* w1T   = (u16*)(ws + 95420672);
  u16* w2T   = (u16*)(ws + 95944960);
  u16* hdn   = (u16*)(ws + 51380224);      // overlays WA/WB (dead by FFN)

  (void)in_sizes; (void)n_in; (void)out_size; (void)ws_size;

  kcvtall<<<1024,256,0,stream>>>(wqkv, wout, w1, w2, wqkvT, woutT, w1T, w2T);

  for (int i=0;i<2;i++){
    kln<<<4096,256,0,stream>>>(i==0 ? x : y, ln1g + i*256, ln1b + i*256, xn);
    kgemm2<EPI_QKV><<<dim3(128,6),256,0,stream>>>(xn, wqkvT + (long)i*196608, 256, 256, 256,
        nullptr, nullptr, 0, qb,kb,vb, ql,kl);
    kattn23<<<dim3(16,32),256,0,stream>>>(ql, kl, X, XT, cs_p, kb, vb, num_p, den_p);

    // ---- pinv: kw0 (scal + W0 + h0) -> 5x kiter -> ktail (g1 chain + U) ----
    kw0<<<256,256,0,stream>>>(cs_p, scal, num_p, den_p, X, WA, h0b);
    u16 *Wi = WA, *Wo = WB, *hi = h0b, *ho = hA;
    for (int it=0; it<5; it++){
      kiter<<<256,256,0,stream>>>(Wi, Wo, hi, ho);
      u16* t = Wi; Wi = Wo; Wo = t;
      hi = ho; ho = (ho == hA) ? hB : hA;
    }
    ktail<<<32,256,0,stream>>>(Wi, hi, XT, scal, uT);

    kattn1u<<<dim3(32,32),256,0,stream>>>(qb, kl, uT, vb, resw + i*264, aoutb);
    kgemm<EPI_BIAS_RES><<<dim3(128,4),256,0,stream>>>(aoutb, woutT + (long)i*65536, 256,256,256,
        bout + i*256, i==0 ? x : y, y, nullptr, 256);
    kln<<<4096,256,0,stream>>>(y, ln2g + i*256, ln2b + i*256, xn);
    kgemm2<EPI_BIAS_GELU><<<dim3(128,4),256,0,stream>>>(xn, w1T + (long)i*131072, 256, 256, 256,
        b1 + i*512, hdn, 512, nullptr,nullptr,nullptr, nullptr,nullptr);
    kgemm<EPI_BIAS_RES><<<dim3(128,4),256,0,stream>>>(hdn, w2T + (long)i*131072, 512,512,512,
        b2 + i*256, y, y, nullptr, 256);
  }
}

// Round 4
// 536.651 us; speedup vs baseline: 5.2205x; 1.0111x over previous
//
#include <hip/hip_runtime.h>
#include <math.h>

typedef float f32x4 __attribute__((ext_vector_type(4)));
typedef short s16x8 __attribute__((ext_vector_type(8)));
typedef unsigned short u16;
typedef unsigned int u32;

#define MFMA16(a,b,c) __builtin_amdgcn_mfma_f32_16x16x32_bf16((a),(b),(c),0,0,0)
#define AS1 __attribute__((address_space(1)))
#define AS3 __attribute__((address_space(3)))

__device__ __forceinline__ void dma16(const u16* g, u16* l){
  __builtin_amdgcn_global_load_lds((const AS1 u32*)g, (AS3 u32*)l, 16, 0, 0);
}

__device__ __forceinline__ float bf2f(u16 u){
  union { unsigned int i; float f; } v; v.i = ((unsigned int)u)<<16; return v.f;
}
__device__ __forceinline__ u16 f2bf(float f){
  union { float f; unsigned int i; } v; v.f = f;
  unsigned int x = v.i;
  return (u16)((x + 0x7fffu + ((x>>16)&1u))>>16);
}

enum { EPI_QKV=0, EPI_BIAS_GELU=3 };

// ---------------------------------------------------------------------------
// kgemm2: BM=128, BN=128, BK=32, 4x4 frags/wave; DMA staging + swizzle.
// ---------------------------------------------------------------------------
template<int EPI>
__global__ __launch_bounds__(256)
void kgemm2(const u16* __restrict__ A, const u16* __restrict__ BT, int K, int lda, int ldb,
            const float* __restrict__ bias, u16* __restrict__ outb, int ldc,
            u16* __restrict__ qo, u16* __restrict__ ko, u16* __restrict__ vo,
            u16* __restrict__ qlm, u16* __restrict__ klm)
{
  __shared__ __align__(16) u16 As[128*32];
  __shared__ __align__(16) u16 Bs[128*32];
  const int tid = threadIdx.x;
  const int w = tid>>6, wy = w>>1, wx = w&1, l = tid&63, q = l>>4, ln = l&15;
  const int m0 = blockIdx.x*128, n0 = blockIdx.y*128;
  const int lrow = l>>2, lch = l&3;

  f32x4 acc[4][4];
  #pragma unroll
  for (int i=0;i<4;i++)
    #pragma unroll
    for (int j=0;j<4;j++){ acc[i][j][0]=0.f; acc[i][j][1]=0.f; acc[i][j][2]=0.f; acc[i][j][3]=0.f; }

  for (int k0=0; k0<K; k0+=32){
    #pragma unroll
    for (int c=0;c<2;c++){
      int row = 32*w + 16*c + lrow;
      int gch = lch ^ ((row>>1)&3);
      dma16(A + (long)(m0+row)*lda + k0 + gch*8, &As[(32*w+16*c)*32]);
      dma16(BT + (long)(n0+row)*ldb + k0 + gch*8, &Bs[(32*w+16*c)*32]);
    }
    __syncthreads();
    s16x8 af[4], bfr[4];
    #pragma unroll
    for (int mt=0;mt<4;mt++){
      int row = wy*64 + mt*16 + ln;
      af[mt] = *(const s16x8*)&As[row*32 + ((q ^ ((row>>1)&3))<<3)];
    }
    #pragma unroll
    for (int nt=0;nt<4;nt++){
      int row = wx*64 + nt*16 + ln;
      bfr[nt] = *(const s16x8*)&Bs[row*32 + ((q ^ ((row>>1)&3))<<3)];
    }
    #pragma unroll
    for (int mt=0;mt<4;mt++)
      #pragma unroll
      for (int nt=0;nt<4;nt++)
        acc[mt][nt] = MFMA16(af[mt], bfr[nt], acc[mt][nt]);
    __syncthreads();
  }

  #pragma unroll
  for (int mt=0;mt<4;mt++)
  #pragma unroll
  for (int nt=0;nt<4;nt++){
    int ncol = n0 + wx*64 + nt*16 + ln;
    if (EPI==EPI_QKV){
      int sel = ncol>>8, hd = ncol&255, h = hd>>5, d = hd&31;
      u16* dst = sel==0 ? qo : (sel==1 ? ko : vo);
      float sc2 = (sel==0) ? 0.17677669529663689f : 1.f;   // dh^-0.5 on q
      float s = 0.f;
      #pragma unroll
      for (int r=0;r<4;r++){
        int mrow = m0 + wy*64 + mt*16 + q*4 + r;
        int b = mrow>>12, n = mrow&4095;
        float v = acc[mt][nt][r]*sc2;
        dst[(((long)(b*8+h)*4096 + n)<<5) + d] = f2bf(v);
        s += v;
      }
      if (sel < 2){
        s += __shfl_xor(s, 16);
        s += __shfl_xor(s, 32);
        if (q == 0){
          int mrow0 = m0 + wy*64 + mt*16;
          int b = mrow0>>12, grp = (mrow0&4095)>>4;
          u16* ldst = (sel==0) ? qlm : klm;
          ldst[(((long)(b*8+h)*256 + grp)<<5) + d] = f2bf(s*(1.0f/16.0f));
        }
      }
    } else { // EPI_BIAS_GELU
      #pragma unroll
      for (int r=0;r<4;r++){
        int mrow = m0 + wy*64 + mt*16 + q*4 + r;
        float x = acc[mt][nt][r] + bias[ncol];
        float g = 0.5f*x*(1.0f + erff(x*0.70710678118654752f));
        outb[(long)mrow*ldc + ncol] = f2bf(g);
      }
    }
  }
}

// ---------------------------------------------------------------------------
// kgemmLN: BM=128, BN=256 (full rows per block), residual+bias epilogue,
// then in-register LayerNorm -> writes y (f32) AND xn=LN(y) (bf16).
// Replaces kgemm<EPI_BIAS_RES> + kln pairs.
// ---------------------------------------------------------------------------
__global__ __launch_bounds__(256)
void kgemmLN(const u16* __restrict__ A, const u16* __restrict__ BT, int K,
             const float* __restrict__ bias, const float* __restrict__ base,
             float* __restrict__ yout,
             const float* __restrict__ lng, const float* __restrict__ lnb,
             u16* __restrict__ xnout)
{
  __shared__ __align__(16) u16 As[128*32];
  __shared__ __align__(16) u16 Bs[256*32];
  const int tid = threadIdx.x;
  const int w = tid>>6, l = tid&63, q = l>>4, ln = l&15;
  const int m0 = blockIdx.x*128;
  const int lrow = l>>2, lch = l&3;

  f32x4 acc[2][16];
  #pragma unroll
  for (int i=0;i<2;i++)
    #pragma unroll
    for (int j=0;j<16;j++){ acc[i][j][0]=0.f; acc[i][j][1]=0.f; acc[i][j][2]=0.f; acc[i][j][3]=0.f; }

  for (int k0=0; k0<K; k0+=32){
    #pragma unroll
    for (int c=0;c<2;c++){
      int row = 32*w + 16*c + lrow;
      int gch = lch ^ ((row>>1)&3);
      dma16(A + (long)(m0+row)*K + k0 + gch*8, &As[(32*w+16*c)*32]);
    }
    #pragma unroll
    for (int c=0;c<4;c++){
      int row = 64*w + 16*c + lrow;
      int gch = lch ^ ((row>>1)&3);
      dma16(BT + (long)row*K + k0 + gch*8, &Bs[(64*w+16*c)*32]);
    }
    __syncthreads();
    s16x8 af[2];
    #pragma unroll
    for (int mt=0;mt<2;mt++){
      int row = w*32 + mt*16 + ln;
      af[mt] = *(const s16x8*)&As[row*32 + ((q ^ ((row>>1)&3))<<3)];
    }
    #pragma unroll
    for (int nt=0;nt<16;nt++){
      int row = nt*16 + ln;
      s16x8 bfr = *(const s16x8*)&Bs[row*32 + ((q ^ ((row>>1)&3))<<3)];
      acc[0][nt] = MFMA16(af[0], bfr, acc[0][nt]);
      acc[1][nt] = MFMA16(af[1], bfr, acc[1][nt]);
    }
    __syncthreads();
  }

  // epilogue: residual + bias (overwrite acc with final f32 y values)
  float rb[16];
  #pragma unroll
  for (int nt=0;nt<16;nt++) rb[nt] = bias[nt*16 + ln];
  #pragma unroll
  for (int mt=0;mt<2;mt++)
  #pragma unroll
  for (int r=0;r<4;r++){
    long rowb = (long)(m0 + w*32 + mt*16 + q*4 + r)*256;
    #pragma unroll
    for (int nt=0;nt<16;nt++){
      int col = nt*16 + ln;
      float v = base[rowb + col] + acc[mt][nt][r] + rb[nt];
      acc[mt][nt][r] = v;
      yout[rowb + col] = v;
    }
  }
  // LayerNorm per row (16-lane reduce within q-group)
  float mu[2][4], rs[2][4];
  #pragma unroll
  for (int mt=0;mt<2;mt++)
  #pragma unroll
  for (int r=0;r<4;r++){
    float s = 0.f;
    #pragma unroll
    for (int nt=0;nt<16;nt++) s += acc[mt][nt][r];
    s += __shfl_xor(s,1); s += __shfl_xor(s,2); s += __shfl_xor(s,4); s += __shfl_xor(s,8);
    mu[mt][r] = s*(1.0f/256.0f);
  }
  #pragma unroll
  for (int mt=0;mt<2;mt++)
  #pragma unroll
  for (int r=0;r<4;r++){
    float vs = 0.f;
    #pragma unroll
    for (int nt=0;nt<16;nt++){ float d = acc[mt][nt][r]-mu[mt][r]; vs += d*d; }
    vs += __shfl_xor(vs,1); vs += __shfl_xor(vs,2); vs += __shfl_xor(vs,4); vs += __shfl_xor(vs,8);
    rs[mt][r] = rsqrtf(vs*(1.0f/256.0f) + 1e-5f);
  }
  float rg[16], rbb[16];
  #pragma unroll
  for (int nt=0;nt<16;nt++){ int col = nt*16+ln; rg[nt]=lng[col]; rbb[nt]=lnb[col]; }
  #pragma unroll
  for (int mt=0;mt<2;mt++)
  #pragma unroll
  for (int r=0;r<4;r++){
    long rowb = (long)(m0 + w*32 + mt*16 + q*4 + r)*256;
    #pragma unroll
    for (int nt=0;nt<16;nt++){
      int col = nt*16 + ln;
      float d = acc[mt][nt][r]-mu[mt][r];
      xnout[rowb + col] = f2bf(d*rs[mt][r]*rg[nt] + rbb[nt]);
    }
  }
}

// ---------------------------------------------------------------------------
// Fused pinv: full 256x256 W resident in LDS (128 KB) + 16 KB t-slab.
// 512 threads (8 waves -> 2 waves/SIMD at 1 block/CU).
// ---------------------------------------------------------------------------
__device__ __forceinline__ int swidx(int row, int col){
  int cc = col>>3;
  int sl = (cc&24)|((cc&7)^((row>>1)&7));
  return row*256 + sl*8 + (col&7);
}

// stage 256x256 bf16 (131072B), 8 waves
__device__ __forceinline__ void stage256(const u16* __restrict__ g, u16* lds, int w, int l){
  const int drow = l>>5, dch = l&31;
  #pragma unroll
  for (int c=0;c<16;c++){
    int base = (c*8 + w)*2;
    int row = base + drow;
    int gch = (dch&24) | ((dch&7) ^ ((row>>1)&7));
    dma16(g + (long)row*256 + gch*8, &lds[base*256]);
  }
}

// stage 32x256 bf16 (16KB), 8 waves
__device__ __forceinline__ void stage32(const u16* __restrict__ g, u16* lds, int w, int l){
  const int drow = l>>5, dch = l&31;
  #pragma unroll
  for (int c=0;c<2;c++){
    int base = (c*8 + w)*2;
    int row = base + drow;
    int gch = (dch&24) | ((dch&7) ^ ((row>>1)&7));
    dma16(g + (long)row*256 + gch*8, &lds[base*256]);
  }
}

// t[32x256] = A(rows arow0..+31 of aL) @ bL^T, K=256; 8 waves (32 cols each)
__device__ __forceinline__ void mult32(const u16* aL, int arow0, const u16* bL,
                                       int w, int l, f32x4 (&acc)[2][2]){
  const int q=l>>4, ln=l&15, wn0=w*32;
  #pragma unroll
  for (int mt=0;mt<2;mt++)
    #pragma unroll
    for (int nt=0;nt<2;nt++){ acc[mt][nt][0]=0.f; acc[mt][nt][1]=0.f; acc[mt][nt][2]=0.f; acc[mt][nt][3]=0.f; }
  #pragma unroll
  for (int kq=0;kq<8;kq++){
    int ca = kq*4+q;
    s16x8 af[2];
    #pragma unroll
    for (int mt=0;mt<2;mt++){
      int r = arow0 + mt*16 + ln;
      af[mt] = *(const s16x8*)&aL[r*256 + (((ca&24)|((ca&7)^((r>>1)&7)))<<3)];
    }
    #pragma unroll
    for (int nt=0;nt<2;nt++){
      int n = wn0 + nt*16 + ln;
      s16x8 bfr = *(const s16x8*)&bL[n*256 + (((ca&24)|((ca&7)^((n>>1)&7)))<<3)];
      acc[0][nt] = MFMA16(af[0], bfr, acc[0][nt]);
      acc[1][nt] = MFMA16(af[1], bfr, acc[1][nt]);
    }
  }
}

__device__ __forceinline__ void polyinit13(const u16* aL, int arow0, int w, int l, f32x4 (&poly)[2][2]){
  const int q=l>>4, ln=l&15, wn0=w*32;
  #pragma unroll
  for (int mt=0;mt<2;mt++)
  #pragma unroll
  for (int nt=0;nt<2;nt++)
  #pragma unroll
  for (int r=0;r<4;r++){
    int row = arow0 + mt*16 + q*4 + r;
    int col = wn0 + nt*16 + ln;
    poly[mt][nt][r] = 13.f*bf2f(aL[swidx(row,col)]);
  }
}

__device__ __forceinline__ void polyaxpy(f32x4 (&poly)[2][2], const f32x4 (&acc)[2][2], float sc){
  #pragma unroll
  for (int mt=0;mt<2;mt++)
    #pragma unroll
    for (int nt=0;nt<2;nt++)
      #pragma unroll
      for (int r=0;r<4;r++) poly[mt][nt][r] += sc*acc[mt][nt][r];
}

__device__ __forceinline__ void writeT(u16* Ts, const f32x4 (&acc)[2][2], int w, int l, float sc){
  const int q=l>>4, ln=l&15, wn0=w*32;
  #pragma unroll
  for (int mt=0;mt<2;mt++)
  #pragma unroll
  for (int nt=0;nt<2;nt++)
  #pragma unroll
  for (int r=0;r<4;r++){
    int row = mt*16 + q*4 + r;
    int col = wn0 + nt*16 + ln;
    Ts[swidx(row,col)] = f2bf(sc*acc[mt][nt][r]);
  }
}

__device__ __forceinline__ void epi_poly(u16* __restrict__ out, int rowbase,
                                         const f32x4 (&poly)[2][2], int w, int l, float sc){
  const int q=l>>4, ln=l&15, wn0=w*32;
  #pragma unroll
  for (int mt=0;mt<2;mt++)
  #pragma unroll
  for (int nt=0;nt<2;nt++)
  #pragma unroll
  for (int r=0;r<4;r++){
    int row = rowbase + mt*16 + q*4 + r;
    int col = wn0 + nt*16 + ln;
    out[(long)row*256 + col] = f2bf(sc*poly[mt][nt][r]);
  }
}

// kw0: W0 = s0*X@X^T slab; self-computed s0 from cs_p; slab0 also preps h0
__global__ __launch_bounds__(512)
void kw0(const float* __restrict__ cs_p, float* __restrict__ scal,
         const float* __restrict__ num_p, const float* __restrict__ den_p,
         const u16* __restrict__ X, u16* __restrict__ W0, u16* __restrict__ h0)
{
  __shared__ __align__(16) u16 Wf[65536];
  __shared__ __align__(16) u16 Ts[8192];
  const int tid=threadIdx.x, w=tid>>6, l=tid&63;
  const int bid=blockIdx.x, xcd=bid&7, j=bid>>3;
  const int batch = xcd*4 + (j>>3), slab = j&7;

  stage256(X + (long)batch*65536, Wf, w, l);   // dma in flight during reduce

  float* red = (float*)Ts;
  float mx = 0.f;
  for (int i=tid;i<8192;i+=512){
    float s = 0.f;
    #pragma unroll
    for (int c=0;c<8;c++) s += cs_p[(long)c*8192 + i];
    mx = fmaxf(mx, s);
  }
  red[tid] = mx; __syncthreads();
  for (int s=256;s>0;s>>=1){ if (tid<s) red[tid] = fmaxf(red[tid], red[tid+s]); __syncthreads(); }
  float s0 = 1.0f/red[0];
  if (bid==0 && tid==0) scal[0] = s0;

  f32x4 acc[2][2];
  mult32(Wf, slab*32, Wf, w, l, acc);
  {
    const int q=l>>4, ln=l&15, wn0=w*32;
    u16* ob = W0 + (long)batch*65536;
    #pragma unroll
    for (int mt=0;mt<2;mt++)
    #pragma unroll
    for (int nt=0;nt<2;nt++)
    #pragma unroll
    for (int r=0;r<4;r++){
      int row = slab*32 + mt*16 + q*4 + r;
      int col = wn0 + nt*16 + ln;
      ob[(long)row*256 + col] = f2bf(acc[mt][nt][r]*s0);
    }
  }

  if (slab==0){
    __syncthreads();
    float (*lt)[257] = (float(*)[257])Wf;
    for (int i=tid;i<8192;i+=512){
      int m = i>>5, d = i&31;
      float sn = 0.f, sd = 0.f;
      #pragma unroll
      for (int c=0;c<8;c++){
        sn += num_p[((long)(c*32+batch))*8192 + i];
        sd += den_p[(c*32+batch)*256 + m];
      }
      lt[d][m] = sn/sd;
    }
    __syncthreads();
    u16* o = h0 + (long)batch*8192;
    for (int j2=tid;j2<8192;j2+=512){
      int d = j2>>8, m = j2&255;
      o[j2] = f2bf(lt[d][m]);
    }
  }
}

// kiter: one Newton iteration. 256 blocks x 512 thr; slab0 also advances h.
__global__ __launch_bounds__(512)
void kiter(const u16* __restrict__ Win, u16* __restrict__ Wout,
           const u16* __restrict__ hin, u16* __restrict__ hout)
{
  __shared__ __align__(16) u16 Wf[65536];
  __shared__ __align__(16) u16 Ts[8192];
  const int tid=threadIdx.x, w=tid>>6, l=tid&63;
  const int bid=blockIdx.x, xcd=bid&7, j=bid>>3;
  const int batch = xcd*4 + (j>>3), slab = j&7;

  stage256(Win + (long)batch*65536, Wf, w, l);
  __syncthreads();

  f32x4 acc[2][2], poly[2][2];
  polyinit13(Wf, slab*32, w, l, poly);
  mult32(Wf, slab*32, Wf, w, l, acc);          // t1 = Wslab@W
  polyaxpy(poly, acc, -15.f);
  writeT(Ts, acc, w, l, 1.f);
  __syncthreads();
  mult32(Ts, 0, Wf, w, l, acc);                // t2
  polyaxpy(poly, acc, 7.f);
  __syncthreads();
  writeT(Ts, acc, w, l, 1.f);
  __syncthreads();
  mult32(Ts, 0, Wf, w, l, acc);                // t3
  polyaxpy(poly, acc, -1.f);
  epi_poly(Wout + (long)batch*65536, slab*32, poly, w, l, 0.25f);

  if (slab==0){
    __syncthreads();                            // all waves past Ts reads
    stage32(hin + (long)batch*8192, Ts, w, l);
    __syncthreads();
    polyinit13(Ts, 0, w, l, poly);
    mult32(Ts, 0, Wf, w, l, acc);               // h@W
    polyaxpy(poly, acc, -15.f);
    __syncthreads(); writeT(Ts, acc, w, l, 1.f); __syncthreads();
    mult32(Ts, 0, Wf, w, l, acc);               // h@W^2
    polyaxpy(poly, acc, 7.f);
    __syncthreads(); writeT(Ts, acc, w, l, 1.f); __syncthreads();
    mult32(Ts, 0, Wf, w, l, acc);               // h@W^3
    polyaxpy(poly, acc, -1.f);
    epi_poly(hout + (long)batch*8192, 0, poly, w, l, 0.25f);
  }
}

// ktail: g1 chain in-LDS, then u = s0*g1@X (via XT)
__global__ __launch_bounds__(512)
void ktail(const u16* __restrict__ W5, const u16* __restrict__ h5,
           const u16* __restrict__ XT, const float* __restrict__ scal,
           u16* __restrict__ uT)
{
  __shared__ __align__(16) u16 Wf[65536];
  __shared__ __align__(16) u16 Ts[8192];
  const int tid=threadIdx.x, w=tid>>6, l=tid&63;
  const int batch = blockIdx.x;

  stage256(W5 + (long)batch*65536, Wf, w, l);
  stage32(h5 + (long)batch*8192, Ts, w, l);
  __syncthreads();

  f32x4 acc[2][2], poly[2][2];
  polyinit13(Ts, 0, w, l, poly);
  mult32(Ts, 0, Wf, w, l, acc);                 // a = h5@W5
  polyaxpy(poly, acc, -15.f);
  __syncthreads(); writeT(Ts, acc, w, l, 1.f); __syncthreads();
  mult32(Ts, 0, Wf, w, l, acc);                 // b
  polyaxpy(poly, acc, 7.f);
  __syncthreads(); writeT(Ts, acc, w, l, 1.f); __syncthreads();
  mult32(Ts, 0, Wf, w, l, acc);                 // c
  polyaxpy(poly, acc, -1.f);
  __syncthreads();
  writeT(Ts, poly, w, l, 0.25f);                // g1 -> Ts
  __syncthreads();
  stage256(XT + (long)batch*65536, Wf, w, l);   // X^T over W5
  __syncthreads();
  mult32(Ts, 0, Wf, w, l, acc);                 // u = g1@X
  const float s0 = scal[0];
  {
    const int q=l>>4, ln=l&15, wn0=w*32;
    u16* ob = uT + (long)batch*8192;
    #pragma unroll
    for (int mt=0;mt<2;mt++)
    #pragma unroll
    for (int nt=0;nt<2;nt++)
    #pragma unroll
    for (int r=0;r<4;r++){
      int row = mt*16 + q*4 + r;
      int col = wn0 + nt*16 + ln;
      ob[(long)row*256 + col] = f2bf(acc[mt][nt][r]*s0);
    }
  }
}

// ---------------------------------------------------------------------------
// Merged attn2 + attn3v (independent; grid (16,32): x<8 attn2, x>=8 attn3v)
// ---------------------------------------------------------------------------
__global__ __launch_bounds__(256)
void kattn23(const u16* __restrict__ ql, const u16* __restrict__ kl,
             u16* __restrict__ X, u16* __restrict__ XT, float* __restrict__ cs_p,
             const u16* __restrict__ kk, const u16* __restrict__ vv,
             float* __restrict__ num_p, float* __restrict__ den_p)
{
  __shared__ __align__(16) u16 Pbuf[4][64][40];
  __shared__ __align__(16) u16 vT[32][40];
  __shared__ float qrow[32][33];
  __shared__ float psum[32][4];
  __shared__ float rsum[32];
  int bh = blockIdx.y;
  int tid = threadIdx.x, w = tid>>6, l = tid&63, q = l>>4, ln = l&15;

  if (blockIdx.x < 8){
    int r0 = blockIdx.x*32;
    int c = tid;
    #pragma unroll
    for (int i=0;i<4;i++){
      int e = c*4+i; int rr = e>>5, dd = e&31;
      qrow[rr][dd] = bf2f(ql[((long)bh*256 + r0+rr)*32 + dd]);
    }
    float kc[32];
    {
      const u16* kp = kl + ((long)bh*256 + c)*32;
      #pragma unroll
      for (int d=0;d<32;d++) kc[d] = bf2f(kp[d]);
    }
    __syncthreads();
    float er[32]; float colacc = 0.f;
    for (int r=0;r<32;r++){
      float s = 0.f;
      #pragma unroll
      for (int d=0;d<32;d++) s += qrow[r][d]*kc[d];
      float e = __expf(s);
      er[r] = e;
      float wsum = e;
      #pragma unroll
      for (int m=1;m<64;m<<=1) wsum += __shfl_xor(wsum, m);
      if (l==0) psum[r][w] = wsum;
    }
    __syncthreads();
    if (c<32) rsum[c] = psum[c][0]+psum[c][1]+psum[c][2]+psum[c][3];
    __syncthreads();
    for (int r=0;r<32;r++){
      float x = er[r]/rsum[r];
      u16 xb = f2bf(x);
      X [((long)bh*256 + r0+r)*256 + c] = xb;
      XT[((long)bh*256 + c)*256 + r0+r] = xb;
      colacc += x;
    }
    cs_p[(long)blockIdx.x*8192 + bh*256 + c] = colacc;
    return;
  }

  int chunk = blockIdx.x - 8;
  f32x4 z4; z4[0]=0.f; z4[1]=0.f; z4[2]=0.f; z4[3]=0.f;
  f32x4 acc[4][2]; f32x4 dacc[4];
  #pragma unroll
  for (int mt=0;mt<4;mt++){ dacc[mt]=z4; acc[mt][0]=z4; acc[mt][1]=z4; }
  const u16* qlb = ql + (long)bh*8192;
  const u16* kb  = kk + (long)bh*131072;
  const u16* vb  = vv + (long)bh*131072;
  int vn = tid>>3, vd = (tid&7)*4;
  for (int s=0;s<16;s++){
    int n0 = chunk*512 + s*32;
    ushort4 vx = *(const ushort4*)(vb + (long)(n0+vn)*32 + vd);
    vT[vd+0][vn]=vx.x; vT[vd+1][vn]=vx.y; vT[vd+2][vn]=vx.z; vT[vd+3][vn]=vx.w;
    __syncthreads();
    s16x8 bk[2];
    #pragma unroll
    for (int nt=0;nt<2;nt++) bk[nt] = *(const s16x8*)(kb + (long)(n0 + nt*16 + ln)*32 + q*8);
    #pragma unroll
    for (int mt=0;mt<4;mt++){
      s16x8 aq = *(const s16x8*)(qlb + (long)(w*64 + mt*16 + ln)*32 + q*8);
      #pragma unroll
      for (int nt=0;nt<2;nt++){
        f32x4 sf = MFMA16(aq, bk[nt], z4);
        f32x4 ef;
        #pragma unroll
        for (int r=0;r<4;r++) ef[r] = __expf(sf[r]);
        dacc[mt] += ef;
        #pragma unroll
        for (int r=0;r<4;r++) Pbuf[w][mt*16 + q*4 + r][nt*16 + ln] = f2bf(ef[r]);
      }
    }
    #pragma unroll
    for (int mt=0;mt<4;mt++){
      s16x8 ap = *(const s16x8*)&Pbuf[w][mt*16 + ln][q*8];
      #pragma unroll
      for (int nt=0;nt<2;nt++){
        s16x8 bv = *(const s16x8*)&vT[nt*16 + ln][q*8];
        acc[mt][nt] = MFMA16(ap, bv, acc[mt][nt]);
      }
    }
    __syncthreads();
  }
  #pragma unroll
  for (int mt=0;mt<4;mt++)
    #pragma unroll
    for (int r=0;r<4;r++){
      float x = dacc[mt][r];
      x += __shfl_xor(x,1); x += __shfl_xor(x,2); x += __shfl_xor(x,4); x += __shfl_xor(x,8);
      dacc[mt][r] = x;
    }
  long pbase = (long)(chunk*32 + bh);
  #pragma unroll
  for (int mt=0;mt<4;mt++)
    #pragma unroll
    for (int nt=0;nt<2;nt++)
      #pragma unroll
      for (int r=0;r<4;r++){
        int mg = w*64 + mt*16 + q*4 + r;
        num_p[pbase*8192 + (long)mg*32 + nt*16 + ln] = acc[mt][nt][r];
      }
  if (ln==0){
    #pragma unroll
    for (int mt=0;mt<4;mt++)
      #pragma unroll
      for (int r=0;r<4;r++)
        den_p[pbase*256 + w*64 + mt*16 + q*4 + r] = dacc[mt][r];
  }
}

// ---------------------------------------------------------------------------
// attn1 fused + depthwise residual conv
// ---------------------------------------------------------------------------
__global__ __launch_bounds__(256)
void kattn1u(const u16* __restrict__ qq, const u16* __restrict__ kl, const u16* __restrict__ uT,
             const u16* __restrict__ vv, const float* __restrict__ rw,
             u16* __restrict__ aoutb)
{
  int nch = blockIdx.x, bh = blockIdx.y;
  int b = bh>>3, h = bh&7;
  int tid = threadIdx.x, w = tid>>6, l = tid&63, q = l>>4, ln = l&15;
  __shared__ __align__(16) u16 Pbuf[4][32][40];
  __shared__ __align__(16) u16 vtile[160][36];
  int r0g = nch*128;
  const u16* vb = vv + (long)bh*131072;
  #pragma unroll
  for (int it=0; it<5; it++){
    int slot = tid + it*256;
    int rr = slot>>3, c = (slot&7)*4;
    int s = r0g - 16 + rr;
    ushort4 val; val.x=0; val.y=0; val.z=0; val.w=0;
    if (s>=0 && s<4096) val = *(const ushort4*)(vb + (long)s*32 + c);
    *(ushort4*)&vtile[rr][c] = val;
  }
  __syncthreads();

  f32x4 z4; z4[0]=0.f; z4[1]=0.f; z4[2]=0.f; z4[3]=0.f;
  f32x4 acc[2][2]; f32x4 dacc[2];
  #pragma unroll
  for (int mt=0;mt<2;mt++){ dacc[mt]=z4; acc[mt][0]=z4; acc[mt][1]=z4; }
  const u16* qb  = qq + (long)bh*131072;
  const u16* klb = kl + (long)bh*8192;
  const u16* ub  = uT + (long)bh*8192;
  int r0 = r0g + w*32;
  for (int s=0;s<8;s++){
    s16x8 bk[2];
    #pragma unroll
    for (int nt=0;nt<2;nt++) bk[nt] = *(const s16x8*)(klb + (long)(s*32 + nt*16 + ln)*32 + q*8);
    #pragma unroll
    for (int mt=0;mt<2;mt++){
      s16x8 aq = *(const s16x8*)(qb + (long)(r0 + mt*16 + ln)*32 + q*8);
      #pragma unroll
      for (int nt=0;nt<2;nt++){
        f32x4 sf = MFMA16(aq, bk[nt], z4);
        f32x4 ef;
        #pragma unroll
        for (int r=0;r<4;r++) ef[r] = __expf(sf[r]);
        dacc[mt] += ef;
        #pragma unroll
        for (int r=0;r<4;r++) Pbuf[w][mt*16 + q*4 + r][nt*16 + ln] = f2bf(ef[r]);
      }
    }
    #pragma unroll
    for (int mt=0;mt<2;mt++){
      s16x8 ap = *(const s16x8*)&Pbuf[w][mt*16 + ln][q*8];
      #pragma unroll
      for (int nt=0;nt<2;nt++){
        s16x8 bu = *(const s16x8*)(ub + (long)(nt*16 + ln)*256 + s*32 + q*8);
        acc[mt][nt] = MFMA16(ap, bu, acc[mt][nt]);
      }
    }
  }
  #pragma unroll
  for (int mt=0;mt<2;mt++)
    #pragma unroll
    for (int r=0;r<4;r++){
      float x = dacc[mt][r];
      x += __shfl_xor(x,1); x += __shfl_xor(x,2); x += __shfl_xor(x,4); x += __shfl_xor(x,8);
      dacc[mt][r] = x;
    }

  const float* wp = rw + h*33;
  float w_[33];
  #pragma unroll
  for (int j=0;j<33;j++) w_[j] = wp[j];

  #pragma unroll
  for (int mt=0;mt<2;mt++){
    int nl = w*32 + mt*16 + q*4;
    #pragma unroll
    for (int nt=0;nt<2;nt++){
      int d = nt*16 + ln;
      float vvv[36];
      #pragma unroll
      for (int j=0;j<36;j++) vvv[j] = bf2f(vtile[nl + j][d]);
      #pragma unroll
      for (int r=0;r<4;r++){
        float cv = 0.f;
        #pragma unroll
        for (int j=0;j<33;j++) cv += w_[j]*vvv[r+j];
        int n = r0 + mt*16 + q*4 + r;
        long oidx = ((long)b*4096 + n)*256 + h*32 + d;
        aoutb[oidx] = f2bf(acc[mt][nt][r]/dacc[mt][r] + cv);
      }
    }
  }
}

// ---------------------------------------------------------------------------
// Merged: LN(x) (blocks 0..4095) + weight transpose/cast (blocks 4096..5119)
// ---------------------------------------------------------------------------
__global__ __launch_bounds__(256)
void kcvtln(const float* __restrict__ xin, const float* __restrict__ lg, const float* __restrict__ lb,
            u16* __restrict__ xn,
            const float* __restrict__ wqkv, const float* __restrict__ wout,
            const float* __restrict__ w1, const float* __restrict__ w2,
            u16* __restrict__ wqkvT, u16* __restrict__ woutT,
            u16* __restrict__ w1T, u16* __restrict__ w2T)
{
  __shared__ float t[32][33];
  int z = blockIdx.x;
  if (z < 4096){
    int w = threadIdx.x>>6, l = threadIdx.x&63;
    long row = (long)z*4 + w;
    float4 v = ((const float4*)(xin + row*256))[l];
    float s = v.x+v.y+v.z+v.w;
    #pragma unroll
    for (int m=1;m<64;m<<=1) s += __shfl_xor(s, m);
    float mu = s*(1.0f/256.0f);
    float dx=v.x-mu, dy=v.y-mu, dz=v.z-mu, dw=v.w-mu;
    float s2 = dx*dx+dy*dy+dz*dz+dw*dw;
    #pragma unroll
    for (int m=1;m<64;m<<=1) s2 += __shfl_xor(s2, m);
    float rs = rsqrtf(s2*(1.0f/256.0f) + 1e-5f);
    float4 gg = ((const float4*)lg)[l];
    float4 bb = ((const float4*)lb)[l];
    ushort4 o;
    o.x = f2bf(dx*rs*gg.x + bb.x);
    o.y = f2bf(dy*rs*gg.y + bb.y);
    o.z = f2bf(dz*rs*gg.z + bb.z);
    o.w = f2bf(dw*rs*gg.w + bb.w);
    *(ushort4*)(xn + row*256 + l*4) = o;
    return;
  }
  z -= 4096;
  const float* src; u16* dst; int K, Nn, bx, by;
  if (z < 384){      int i=z/192, r=z%192; src=wqkv+(long)i*196608; dst=wqkvT+(long)i*196608; K=256; Nn=768; bx=r%24; by=r/24; }
  else if (z < 512){ int zz=z-384; int i=zz/64, r=zz%64; src=wout+(long)i*65536; dst=woutT+(long)i*65536; K=256; Nn=256; bx=r%8; by=r/8; }
  else if (z < 768){ int zz=z-512; int i=zz/128, r=zz%128; src=w1+(long)i*131072; dst=w1T+(long)i*131072; K=256; Nn=512; bx=r%16; by=r/16; }
  else {             int zz=z-768; int i=zz/128, r=zz%128; src=w2+(long)i*131072; dst=w2T+(long)i*131072; K=512; Nn=256; bx=r%8; by=r/8; }
  int n0 = bx*32, k0 = by*32;
  int tx = threadIdx.x&31, ty = threadIdx.x>>5;
  #pragma unroll
  for (int i=0;i<4;i++) t[ty+i*8][tx] = src[(long)(k0+ty+i*8)*Nn + n0+tx];
  __syncthreads();
  #pragma unroll
  for (int i=0;i<4;i++) dst[(long)(n0+ty+i*8)*K + k0+tx] = f2bf(t[tx][ty+i*8]);
}

// ---------------------------------------------------------------------------
extern "C" void kernel_launch(void* const* d_in, const int* in_sizes, int n_in,
                              void* d_out, int out_size, void* d_ws, size_t ws_size,
                              hipStream_t stream)
{
  const float* x    = (const float*)d_in[0];
  const float* ln1g = (const float*)d_in[1];
  const float* ln1b = (const float*)d_in[2];
  const float* wqkv = (const float*)d_in[3];
  const float* wout = (const float*)d_in[4];
  const float* bout = (const float*)d_in[5];
  const float* resw = (const float*)d_in[6];
  const float* ln2g = (const float*)d_in[7];
  const float* ln2b = (const float*)d_in[8];
  const float* w1   = (const float*)d_in[9];
  const float* b1   = (const float*)d_in[10];
  const float* w2   = (const float*)d_in[11];
  const float* b2   = (const float*)d_in[12];
  float* y = (float*)d_out;
  char* ws = (char*)d_ws;

  u16* xn    = (u16*)(ws + 0);
  u16* qb    = (u16*)(ws + 8388608);
  u16* kb    = (u16*)(ws + 16777216);
  u16* vb    = (u16*)(ws + 25165824);
  u16* ql    = (u16*)(ws + 33554432);
  u16* kl    = (u16*)(ws + 34078720);
  u16* X     = (u16*)(ws + 34603008);
  u16* XT    = (u16*)(ws + 38797312);     // X^T (B-operand of final U GEMM)
  u16* h0b   = (u16*)(ws + 42991616);     // h0 [32][32][256] bf16 (512 KB)
  // pinv work region
  u16* WA    = (u16*)(ws + 51380224);
  u16* WB    = (u16*)(ws + 55574528);
  u16* hA    = (u16*)(ws + 68157440);     // thin h buffers [32][32][256]
  u16* hB    = (u16*)(ws + 72351744);
  float* num_p = (float*)(ws + 76546048);  // 8 MB
  float* den_p = (float*)(ws + 84934656);
  float* cs_p  = (float*)(ws + 85196800);
  float* scal  = (float*)(ws + 85458944);
  u16* uT    = (u16*)(ws + 85459200);
  u16* aoutb = (u16*)(ws + 85983488);
  u16* wqkvT = (u16*)(ws + 94372096);
  u16* woutT = (u16*)(ws + 95158528);
  u16* w1T   = (u16*)(ws + 95420672);
  u16* w2T   = (u16*)(ws + 95944960);
  u16* hdn   = (u16*)(ws + 51380224);      // overlays WA/WB (dead by FFN)

  (void)in_sizes; (void)n_in; (void)out_size; (void)ws_size;

  // LN(x) + weight cvt in one launch
  kcvtln<<<5120,256,0,stream>>>(x, ln1g, ln1b, xn,
      wqkv, wout, w1, w2, wqkvT, woutT, w1T, w2T);

  for (int i=0;i<2;i++){
    // xn: i==0 from kcvtln; i==1 from previous FFN2's fused LN epilogue
    kgemm2<EPI_QKV><<<dim3(128,6),256,0,stream>>>(xn, wqkvT + (long)i*196608, 256, 256, 256,
        nullptr, nullptr, 0, qb,kb,vb, ql,kl);
    kattn23<<<dim3(16,32),256,0,stream>>>(ql, kl, X, XT, cs_p, kb, vb, num_p, den_p);

    // ---- pinv: kw0 (scal + W0 + h0) -> 5x kiter -> ktail (g1 chain + U) ----
    kw0<<<256,512,0,stream>>>(cs_p, scal, num_p, den_p, X, WA, h0b);
    u16 *Wi = WA, *Wo = WB, *hi = h0b, *ho = hA;
    for (int it=0; it<5; it++){
      kiter<<<256,512,0,stream>>>(Wi, Wo, hi, ho);
      u16* t = Wi; Wi = Wo; Wo = t;
      hi = ho; ho = (ho == hA) ? hB : hA;
    }
    ktail<<<32,512,0,stream>>>(Wi, hi, XT, scal, uT);

    kattn1u<<<dim3(32,32),256,0,stream>>>(qb, kl, uT, vb, resw + i*264, aoutb);
    // wout GEMM + residual + LN2 fused -> y (f32) + xn (bf16 for FFN1)
    kgemmLN<<<128,256,0,stream>>>(aoutb, woutT + (long)i*65536, 256,
        bout + i*256, i==0 ? x : y, y, ln2g + i*256, ln2b + i*256, xn);
    kgemm2<EPI_BIAS_GELU><<<dim3(128,4),256,0,stream>>>(xn, w1T + (long)i*131072, 256, 256, 256,
        b1 + i*512, hdn, 512, nullptr,nullptr,nullptr, nullptr,nullptr);
    // FFN2 GEMM + residual + LN1(next) fused -> y + xn (for next QKV; dead on i==1)
    kgemmLN<<<128,256,0,stream>>>(hdn, w2T + (long)i*131072, 512,
        b2 + i*256, y, y, ln1g + 256, ln1b + 256, xn);
  }
}

// Round 5
// 503.235 us; speedup vs baseline: 5.5672x; 1.0664x over previous
//
#include <hip/hip_runtime.h>
#include <math.h>

typedef float f32x4 __attribute__((ext_vector_type(4)));
typedef short s16x8 __attribute__((ext_vector_type(8)));
typedef unsigned short u16;
typedef unsigned int u32;

#define MFMA16(a,b,c) __builtin_amdgcn_mfma_f32_16x16x32_bf16((a),(b),(c),0,0,0)
#define AS1 __attribute__((address_space(1)))
#define AS3 __attribute__((address_space(3)))

__device__ __forceinline__ void dma16(const u16* g, u16* l){
  __builtin_amdgcn_global_load_lds((const AS1 u32*)g, (AS3 u32*)l, 16, 0, 0);
}

__device__ __forceinline__ float bf2f(u16 u){
  union { unsigned int i; float f; } v; v.i = ((unsigned int)u)<<16; return v.f;
}
__device__ __forceinline__ u16 f2bf(float f){
  union { float f; unsigned int i; } v; v.f = f;
  unsigned int x = v.i;
  return (u16)((x + 0x7fffu + ((x>>16)&1u))>>16);
}

enum { EPI_QKV=0, EPI_BIAS_GELU=3 };

// ---------------------------------------------------------------------------
// kgemm2: BM=128, BN=128, BK=32, 4x4 frags/wave; DMA staging + swizzle.
// ---------------------------------------------------------------------------
template<int EPI>
__global__ __launch_bounds__(256)
void kgemm2(const u16* __restrict__ A, const u16* __restrict__ BT, int K, int lda, int ldb,
            const float* __restrict__ bias, u16* __restrict__ outb, int ldc,
            u16* __restrict__ qo, u16* __restrict__ ko, u16* __restrict__ vo,
            u16* __restrict__ qlm, u16* __restrict__ klm)
{
  __shared__ __align__(16) u16 As[128*32];
  __shared__ __align__(16) u16 Bs[128*32];
  const int tid = threadIdx.x;
  const int w = tid>>6, wy = w>>1, wx = w&1, l = tid&63, q = l>>4, ln = l&15;
  const int m0 = blockIdx.x*128, n0 = blockIdx.y*128;
  const int lrow = l>>2, lch = l&3;

  f32x4 acc[4][4];
  #pragma unroll
  for (int i=0;i<4;i++)
    #pragma unroll
    for (int j=0;j<4;j++){ acc[i][j][0]=0.f; acc[i][j][1]=0.f; acc[i][j][2]=0.f; acc[i][j][3]=0.f; }

  for (int k0=0; k0<K; k0+=32){
    #pragma unroll
    for (int c=0;c<2;c++){
      int row = 32*w + 16*c + lrow;
      int gch = lch ^ ((row>>1)&3);
      dma16(A + (long)(m0+row)*lda + k0 + gch*8, &As[(32*w+16*c)*32]);
      dma16(BT + (long)(n0+row)*ldb + k0 + gch*8, &Bs[(32*w+16*c)*32]);
    }
    __syncthreads();
    s16x8 af[4], bfr[4];
    #pragma unroll
    for (int mt=0;mt<4;mt++){
      int row = wy*64 + mt*16 + ln;
      af[mt] = *(const s16x8*)&As[row*32 + ((q ^ ((row>>1)&3))<<3)];
    }
    #pragma unroll
    for (int nt=0;nt<4;nt++){
      int row = wx*64 + nt*16 + ln;
      bfr[nt] = *(const s16x8*)&Bs[row*32 + ((q ^ ((row>>1)&3))<<3)];
    }
    #pragma unroll
    for (int mt=0;mt<4;mt++)
      #pragma unroll
      for (int nt=0;nt<4;nt++)
        acc[mt][nt] = MFMA16(af[mt], bfr[nt], acc[mt][nt]);
    __syncthreads();
  }

  #pragma unroll
  for (int mt=0;mt<4;mt++)
  #pragma unroll
  for (int nt=0;nt<4;nt++){
    int ncol = n0 + wx*64 + nt*16 + ln;
    if (EPI==EPI_QKV){
      int sel = ncol>>8, hd = ncol&255, h = hd>>5, d = hd&31;
      u16* dst = sel==0 ? qo : (sel==1 ? ko : vo);
      float sc2 = (sel==0) ? 0.17677669529663689f : 1.f;   // dh^-0.5 on q
      float s = 0.f;
      #pragma unroll
      for (int r=0;r<4;r++){
        int mrow = m0 + wy*64 + mt*16 + q*4 + r;
        int b = mrow>>12, n = mrow&4095;
        float v = acc[mt][nt][r]*sc2;
        dst[(((long)(b*8+h)*4096 + n)<<5) + d] = f2bf(v);
        s += v;
      }
      if (sel < 2){
        s += __shfl_xor(s, 16);
        s += __shfl_xor(s, 32);
        if (q == 0){
          int mrow0 = m0 + wy*64 + mt*16;
          int b = mrow0>>12, grp = (mrow0&4095)>>4;
          u16* ldst = (sel==0) ? qlm : klm;
          ldst[(((long)(b*8+h)*256 + grp)<<5) + d] = f2bf(s*(1.0f/16.0f));
        }
      }
    } else { // EPI_BIAS_GELU
      #pragma unroll
      for (int r=0;r<4;r++){
        int mrow = m0 + wy*64 + mt*16 + q*4 + r;
        float x = acc[mt][nt][r] + bias[ncol];
        float g = 0.5f*x*(1.0f + erff(x*0.70710678118654752f));
        outb[(long)mrow*ldc + ncol] = f2bf(g);
      }
    }
  }
}

// ---------------------------------------------------------------------------
// kgemmLN: BM=64, BN=256 (full rows per block, 256 blocks = full GPU),
// 4x4 frags/wave; residual+bias, then in-register LayerNorm with cross-wave
// combine -> writes y (f32) AND xn=LN(y) (bf16).
// ---------------------------------------------------------------------------
__global__ __launch_bounds__(256)
void kgemmLN(const u16* __restrict__ A, const u16* __restrict__ BT, int K,
             const float* __restrict__ bias, const float* __restrict__ base,
             float* __restrict__ yout,
             const float* __restrict__ lng, const float* __restrict__ lnb,
             u16* __restrict__ xnout)
{
  __shared__ __align__(16) u16 As[64*32];
  __shared__ __align__(16) u16 Bs[256*32];
  __shared__ float red[64][4];
  const int tid = threadIdx.x;
  const int w = tid>>6, l = tid&63, q = l>>4, ln = l&15;
  const int m0 = blockIdx.x*64;

  f32x4 acc[4][4];   // row = mt*16+q*4+r, col = w*64+nt*16+ln
  #pragma unroll
  for (int i=0;i<4;i++)
    #pragma unroll
    for (int j=0;j<4;j++){ acc[i][j][0]=0.f; acc[i][j][1]=0.f; acc[i][j][2]=0.f; acc[i][j][3]=0.f; }

  for (int k0=0; k0<K; k0+=32){
    {
      int row = w*16 + (l>>2);
      int gch = (l&3) ^ ((row>>1)&3);
      dma16(A + (long)(m0+row)*K + k0 + gch*8, &As[(w*16)*32]);
    }
    #pragma unroll
    for (int c=0;c<4;c++){
      int row = c*64 + w*16 + (l>>2);
      int gch = (l&3) ^ ((row>>1)&3);
      dma16(BT + (long)row*K + k0 + gch*8, &Bs[(c*64+w*16)*32]);
    }
    __syncthreads();
    s16x8 af[4], bfr[4];
    #pragma unroll
    for (int mt=0;mt<4;mt++){
      int row = mt*16 + ln;
      af[mt] = *(const s16x8*)&As[row*32 + ((q ^ ((row>>1)&3))<<3)];
    }
    #pragma unroll
    for (int nt=0;nt<4;nt++){
      int row = w*64 + nt*16 + ln;
      bfr[nt] = *(const s16x8*)&Bs[row*32 + ((q ^ ((row>>1)&3))<<3)];
    }
    #pragma unroll
    for (int mt=0;mt<4;mt++)
      #pragma unroll
      for (int nt=0;nt<4;nt++)
        acc[mt][nt] = MFMA16(af[mt], bfr[nt], acc[mt][nt]);
    __syncthreads();
  }

  // residual + bias, write y
  float rb[4];
  #pragma unroll
  for (int nt=0;nt<4;nt++) rb[nt] = bias[w*64 + nt*16 + ln];
  #pragma unroll
  for (int mt=0;mt<4;mt++)
  #pragma unroll
  for (int r=0;r<4;r++){
    long rowb = (long)(m0 + mt*16 + q*4 + r)*256;
    #pragma unroll
    for (int nt=0;nt<4;nt++){
      int col = w*64 + nt*16 + ln;
      float v = base[rowb + col] + acc[mt][nt][r] + rb[nt];
      acc[mt][nt][r] = v;
      yout[rowb + col] = v;
    }
  }
  // mean: per-lane over 4 nt, 16-lane shuffle, cross-wave via red
  #pragma unroll
  for (int mt=0;mt<4;mt++)
  #pragma unroll
  for (int r=0;r<4;r++){
    float s = acc[mt][0][r]+acc[mt][1][r]+acc[mt][2][r]+acc[mt][3][r];
    s += __shfl_xor(s,1); s += __shfl_xor(s,2); s += __shfl_xor(s,4); s += __shfl_xor(s,8);
    if (ln==0) red[mt*16+q*4+r][w] = s;
  }
  __syncthreads();
  float mu[4][4];
  #pragma unroll
  for (int mt=0;mt<4;mt++)
  #pragma unroll
  for (int r=0;r<4;r++){
    int row = mt*16+q*4+r;
    mu[mt][r] = (red[row][0]+red[row][1]+red[row][2]+red[row][3])*(1.0f/256.0f);
  }
  __syncthreads();
  #pragma unroll
  for (int mt=0;mt<4;mt++)
  #pragma unroll
  for (int r=0;r<4;r++){
    float vs = 0.f;
    #pragma unroll
    for (int nt=0;nt<4;nt++){ float d = acc[mt][nt][r]-mu[mt][r]; vs += d*d; }
    vs += __shfl_xor(vs,1); vs += __shfl_xor(vs,2); vs += __shfl_xor(vs,4); vs += __shfl_xor(vs,8);
    if (ln==0) red[mt*16+q*4+r][w] = vs;
  }
  __syncthreads();
  float rg[4], rbb[4];
  #pragma unroll
  for (int nt=0;nt<4;nt++){ int col = w*64+nt*16+ln; rg[nt]=lng[col]; rbb[nt]=lnb[col]; }
  #pragma unroll
  for (int mt=0;mt<4;mt++)
  #pragma unroll
  for (int r=0;r<4;r++){
    int row = mt*16+q*4+r;
    float rs = rsqrtf((red[row][0]+red[row][1]+red[row][2]+red[row][3])*(1.0f/256.0f) + 1e-5f);
    long rowb = (long)(m0 + row)*256;
    #pragma unroll
    for (int nt=0;nt<4;nt++){
      int col = w*64 + nt*16 + ln;
      float d = acc[mt][nt][r]-mu[mt][r];
      xnout[rowb + col] = f2bf(d*rs*rg[nt] + rbb[nt]);
    }
  }
}

// ---------------------------------------------------------------------------
// Fused pinv: full 256x256 W resident in LDS + reg-cached B frags.
// 512 threads (8 waves). W' = 0.25(13W -15W^2 +7W^3 -W^4) per 32-row slab;
// h rows split across slab0 (rows 0-15) and slab4 (rows 16-31).
// ---------------------------------------------------------------------------
__device__ __forceinline__ int swidx(int row, int col){
  int cc = col>>3;
  int sl = (cc&24)|((cc&7)^((row>>1)&7));
  return row*256 + sl*8 + (col&7);
}
__device__ __forceinline__ int slot8(int ca, int row){
  return ((ca&24)|((ca&7)^((row>>1)&7)))<<3;
}

// stage 256x256 bf16 (131072B), 8 waves
__device__ __forceinline__ void stage256(const u16* __restrict__ g, u16* lds, int w, int l){
  const int drow = l>>5, dch = l&31;
  #pragma unroll
  for (int c=0;c<16;c++){
    int base = (c*8 + w)*2;
    int row = base + drow;
    int gch = (dch&24) | ((dch&7) ^ ((row>>1)&7));
    dma16(g + (long)row*256 + gch*8, &lds[base*256]);
  }
}
// stage 32x256 (16KB), 8 waves
__device__ __forceinline__ void stage32(const u16* __restrict__ g, u16* lds, int w, int l){
  const int drow = l>>5, dch = l&31;
  #pragma unroll
  for (int c=0;c<2;c++){
    int base = (c*8 + w)*2;
    int row = base + drow;
    int gch = (dch&24) | ((dch&7) ^ ((row>>1)&7));
    dma16(g + (long)row*256 + gch*8, &lds[base*256]);
  }
}
// stage 16x256 (8KB), 8 waves (2 rows/wave)
__device__ __forceinline__ void stage16(const u16* __restrict__ g, u16* lds, int w, int l){
  const int drow = l>>5, dch = l&31;
  int row = w*2 + drow;
  int gch = (dch&24) | ((dch&7) ^ ((row>>1)&7));
  dma16(g + (long)row*256 + gch*8, &lds[(w*2)*256]);
}

// preload this wave's 32 B-columns (rows wn0..+31 of bL) across K into regs
__device__ __forceinline__ void loadBf(const u16* bL, int w, int l, s16x8 (&bw)[2][8]){
  const int q=l>>4, ln=l&15, wn0=w*32;
  #pragma unroll
  for (int nt=0;nt<2;nt++)
    #pragma unroll
    for (int kq=0;kq<8;kq++){
      int n = wn0 + nt*16 + ln, ca = kq*4+q;
      bw[nt][kq] = *(const s16x8*)&bL[n*256 + slot8(ca, n)];
    }
}

// acc = A(rows arow0..+31 of aL) @ B(regs), K=256
__device__ __forceinline__ void multAr(const u16* aL, int arow0, const s16x8 (&bw)[2][8],
                                       int l, f32x4 (&acc)[2][2]){
  const int q=l>>4, ln=l&15;
  #pragma unroll
  for (int mt=0;mt<2;mt++)
    #pragma unroll
    for (int nt=0;nt<2;nt++){ acc[mt][nt][0]=0.f; acc[mt][nt][1]=0.f; acc[mt][nt][2]=0.f; acc[mt][nt][3]=0.f; }
  #pragma unroll
  for (int kq=0;kq<8;kq++){
    int ca = kq*4+q;
    s16x8 af[2];
    #pragma unroll
    for (int mt=0;mt<2;mt++){
      int r = arow0 + mt*16 + ln;
      af[mt] = *(const s16x8*)&aL[r*256 + slot8(ca, r)];
    }
    #pragma unroll
    for (int mt=0;mt<2;mt++)
      #pragma unroll
      for (int nt=0;nt<2;nt++)
        acc[mt][nt] = MFMA16(af[mt], bw[nt][kq], acc[mt][nt]);
  }
}

// hacc = H(16 rows of hL) @ B(regs)
__device__ __forceinline__ void multHr(const u16* hL, const s16x8 (&bw)[2][8],
                                       int l, f32x4 (&hacc)[2]){
  const int q=l>>4, ln=l&15;
  hacc[0][0]=0.f; hacc[0][1]=0.f; hacc[0][2]=0.f; hacc[0][3]=0.f;
  hacc[1][0]=0.f; hacc[1][1]=0.f; hacc[1][2]=0.f; hacc[1][3]=0.f;
  #pragma unroll
  for (int kq=0;kq<8;kq++){
    int ca = kq*4+q;
    s16x8 af = *(const s16x8*)&hL[ln*256 + slot8(ca, ln)];
    hacc[0] = MFMA16(af, bw[0][kq], hacc[0]);
    hacc[1] = MFMA16(af, bw[1][kq], hacc[1]);
  }
}

__device__ __forceinline__ void polyinit13(const u16* aL, int arow0, int w, int l, f32x4 (&poly)[2][2]){
  const int q=l>>4, ln=l&15, wn0=w*32;
  #pragma unroll
  for (int mt=0;mt<2;mt++)
  #pragma unroll
  for (int nt=0;nt<2;nt++)
  #pragma unroll
  for (int r=0;r<4;r++){
    int row = arow0 + mt*16 + q*4 + r;
    int col = wn0 + nt*16 + ln;
    poly[mt][nt][r] = 13.f*bf2f(aL[swidx(row,col)]);
  }
}
__device__ __forceinline__ void init13H(const u16* hL, int w, int l, f32x4 (&hpoly)[2]){
  const int q=l>>4, ln=l&15, wn0=w*32;
  #pragma unroll
  for (int nt=0;nt<2;nt++)
  #pragma unroll
  for (int r=0;r<4;r++)
    hpoly[nt][r] = 13.f*bf2f(hL[swidx(q*4+r, wn0+nt*16+ln)]);
}
__device__ __forceinline__ void polyaxpy(f32x4 (&poly)[2][2], const f32x4 (&acc)[2][2], float sc){
  #pragma unroll
  for (int mt=0;mt<2;mt++)
    #pragma unroll
    for (int nt=0;nt<2;nt++)
      #pragma unroll
      for (int r=0;r<4;r++) poly[mt][nt][r] += sc*acc[mt][nt][r];
}
__device__ __forceinline__ void axpyH(f32x4 (&hpoly)[2], const f32x4 (&hacc)[2], float sc){
  #pragma unroll
  for (int nt=0;nt<2;nt++)
    #pragma unroll
    for (int r=0;r<4;r++) hpoly[nt][r] += sc*hacc[nt][r];
}
__device__ __forceinline__ void writeT(u16* Ts, const f32x4 (&acc)[2][2], int w, int l, float sc){
  const int q=l>>4, ln=l&15, wn0=w*32;
  #pragma unroll
  for (int mt=0;mt<2;mt++)
  #pragma unroll
  for (int nt=0;nt<2;nt++)
  #pragma unroll
  for (int r=0;r<4;r++){
    int row = mt*16 + q*4 + r;
    int col = wn0 + nt*16 + ln;
    Ts[swidx(row,col)] = f2bf(sc*acc[mt][nt][r]);
  }
}
__device__ __forceinline__ void writeH(u16* Hs, const f32x4 (&hacc)[2], int w, int l){
  const int q=l>>4, ln=l&15, wn0=w*32;
  #pragma unroll
  for (int nt=0;nt<2;nt++)
  #pragma unroll
  for (int r=0;r<4;r++)
    Hs[swidx(q*4+r, wn0+nt*16+ln)] = f2bf(hacc[nt][r]);
}
__device__ __forceinline__ void epi_poly(u16* __restrict__ out, int rowbase,
                                         const f32x4 (&poly)[2][2], int w, int l, float sc){
  const int q=l>>4, ln=l&15, wn0=w*32;
  #pragma unroll
  for (int mt=0;mt<2;mt++)
  #pragma unroll
  for (int nt=0;nt<2;nt++)
  #pragma unroll
  for (int r=0;r<4;r++){
    int row = rowbase + mt*16 + q*4 + r;
    int col = wn0 + nt*16 + ln;
    out[(long)row*256 + col] = f2bf(sc*poly[mt][nt][r]);
  }
}
__device__ __forceinline__ void epiH(u16* __restrict__ out, const f32x4 (&hpoly)[2],
                                     int w, int l, float sc){
  const int q=l>>4, ln=l&15, wn0=w*32;
  #pragma unroll
  for (int nt=0;nt<2;nt++)
  #pragma unroll
  for (int r=0;r<4;r++)
    out[(long)(q*4+r)*256 + wn0+nt*16+ln] = f2bf(sc*hpoly[nt][r]);
}

// legacy LDS-B mult (kw0 only: single phase, preload is neutral)
__device__ __forceinline__ void mult32(const u16* aL, int arow0, const u16* bL,
                                       int w, int l, f32x4 (&acc)[2][2]){
  const int q=l>>4, ln=l&15, wn0=w*32;
  #pragma unroll
  for (int mt=0;mt<2;mt++)
    #pragma unroll
    for (int nt=0;nt<2;nt++){ acc[mt][nt][0]=0.f; acc[mt][nt][1]=0.f; acc[mt][nt][2]=0.f; acc[mt][nt][3]=0.f; }
  #pragma unroll
  for (int kq=0;kq<8;kq++){
    int ca = kq*4+q;
    s16x8 af[2];
    #pragma unroll
    for (int mt=0;mt<2;mt++){
      int r = arow0 + mt*16 + ln;
      af[mt] = *(const s16x8*)&aL[r*256 + slot8(ca,r)];
    }
    #pragma unroll
    for (int nt=0;nt<2;nt++){
      int n = wn0 + nt*16 + ln;
      s16x8 bfr = *(const s16x8*)&bL[n*256 + slot8(ca,n)];
      acc[0][nt] = MFMA16(af[0], bfr, acc[0][nt]);
      acc[1][nt] = MFMA16(af[1], bfr, acc[1][nt]);
    }
  }
}

// kw0: W0 = s0*X@X^T slab; self-computed s0 from cs_p; slab0 also preps h0
__global__ __launch_bounds__(512)
void kw0(const float* __restrict__ cs_p, float* __restrict__ scal,
         const float* __restrict__ num_p, const float* __restrict__ den_p,
         const u16* __restrict__ X, u16* __restrict__ W0, u16* __restrict__ h0)
{
  __shared__ __align__(16) u16 Wf[65536];
  __shared__ __align__(16) u16 Ts[8192];
  const int tid=threadIdx.x, w=tid>>6, l=tid&63;
  const int bid=blockIdx.x, xcd=bid&7, j=bid>>3;
  const int batch = xcd*4 + (j>>3), slab = j&7;

  stage256(X + (long)batch*65536, Wf, w, l);   // dma in flight during reduce

  float* red = (float*)Ts;
  float mx = 0.f;
  for (int i=tid;i<8192;i+=512){
    float s = 0.f;
    #pragma unroll
    for (int c=0;c<8;c++) s += cs_p[(long)c*8192 + i];
    mx = fmaxf(mx, s);
  }
  red[tid] = mx; __syncthreads();
  for (int s=256;s>0;s>>=1){ if (tid<s) red[tid] = fmaxf(red[tid], red[tid+s]); __syncthreads(); }
  float s0 = 1.0f/red[0];
  if (bid==0 && tid==0) scal[0] = s0;

  f32x4 acc[2][2];
  mult32(Wf, slab*32, Wf, w, l, acc);
  {
    const int q=l>>4, ln=l&15, wn0=w*32;
    u16* ob = W0 + (long)batch*65536;
    #pragma unroll
    for (int mt=0;mt<2;mt++)
    #pragma unroll
    for (int nt=0;nt<2;nt++)
    #pragma unroll
    for (int r=0;r<4;r++){
      int row = slab*32 + mt*16 + q*4 + r;
      int col = wn0 + nt*16 + ln;
      ob[(long)row*256 + col] = f2bf(acc[mt][nt][r]*s0);
    }
  }

  if (slab==0){
    __syncthreads();
    float (*lt)[257] = (float(*)[257])Wf;
    for (int i=tid;i<8192;i+=512){
      int m = i>>5, d = i&31;
      float sn = 0.f, sd = 0.f;
      #pragma unroll
      for (int c=0;c<8;c++){
        sn += num_p[((long)(c*32+batch))*8192 + i];
        sd += den_p[(c*32+batch)*256 + m];
      }
      lt[d][m] = sn/sd;
    }
    __syncthreads();
    u16* o = h0 + (long)batch*8192;
    for (int j2=tid;j2<8192;j2+=512){
      int d = j2>>8, m = j2&255;
      o[j2] = f2bf(lt[d][m]);
    }
  }
}

// kiter: one Newton iteration. 256 blocks x 512 thr; slab0/slab4 advance h halves.
__global__ __launch_bounds__(512)
void kiter(const u16* __restrict__ Win, u16* __restrict__ Wout,
           const u16* __restrict__ hin, u16* __restrict__ hout)
{
  __shared__ __align__(16) u16 Wf[65536];
  __shared__ __align__(16) u16 Ts[8192];
  __shared__ __align__(16) u16 Hs[4096];
  const int tid=threadIdx.x, w=tid>>6, l=tid&63;
  const int bid=blockIdx.x, xcd=bid&7, j=bid>>3;
  const int batch = xcd*4 + (j>>3), slab = j&7;
  const bool hrole = (slab&3)==0;              // slabs 0 and 4
  const int hr0 = (slab>>2)*16;

  stage256(Win + (long)batch*65536, Wf, w, l);
  if (hrole) stage16(hin + (long)batch*8192 + hr0*256, Hs, w, l);
  __syncthreads();

  s16x8 bw[2][8];
  loadBf(Wf, w, l, bw);

  f32x4 acc[2][2], poly[2][2];
  f32x4 hacc[2], hpoly[2];

  polyinit13(Wf, slab*32, w, l, poly);
  multAr(Wf, slab*32, bw, l, acc);             // t1 = Wslab@W
  polyaxpy(poly, acc, -15.f);
  if (hrole){
    init13H(Hs, w, l, hpoly);
    multHr(Hs, bw, l, hacc);                   // h@W
    axpyH(hpoly, hacc, -15.f);
  }
  __syncthreads();
  writeT(Ts, acc, w, l, 1.f);
  if (hrole) writeH(Hs, hacc, w, l);
  __syncthreads();
  multAr(Ts, 0, bw, l, acc);                   // t2
  polyaxpy(poly, acc, 7.f);
  if (hrole){ multHr(Hs, bw, l, hacc); axpyH(hpoly, hacc, 7.f); }
  __syncthreads();
  writeT(Ts, acc, w, l, 1.f);
  if (hrole) writeH(Hs, hacc, w, l);
  __syncthreads();
  multAr(Ts, 0, bw, l, acc);                   // t3
  polyaxpy(poly, acc, -1.f);
  epi_poly(Wout + (long)batch*65536, slab*32, poly, w, l, 0.25f);
  if (hrole){
    multHr(Hs, bw, l, hacc);
    axpyH(hpoly, hacc, -1.f);
    epiH(hout + (long)batch*8192 + hr0*256, hpoly, w, l, 0.25f);
  }
}

// ktail: g1 chain in-LDS (reg-B), then u = s0*g1@X (via XT restage)
__global__ __launch_bounds__(512)
void ktail(const u16* __restrict__ W5, const u16* __restrict__ h5,
           const u16* __restrict__ XT, const float* __restrict__ scal,
           u16* __restrict__ uT)
{
  __shared__ __align__(16) u16 Wf[65536];
  __shared__ __align__(16) u16 Ts[8192];
  const int tid=threadIdx.x, w=tid>>6, l=tid&63;
  const int batch = blockIdx.x;

  stage256(W5 + (long)batch*65536, Wf, w, l);
  stage32(h5 + (long)batch*8192, Ts, w, l);
  __syncthreads();

  s16x8 bw[2][8];
  loadBf(Wf, w, l, bw);

  f32x4 acc[2][2], poly[2][2];
  polyinit13(Ts, 0, w, l, poly);
  multAr(Ts, 0, bw, l, acc);                   // a = h5@W5
  polyaxpy(poly, acc, -15.f);
  __syncthreads(); writeT(Ts, acc, w, l, 1.f); __syncthreads();
  multAr(Ts, 0, bw, l, acc);                   // b
  polyaxpy(poly, acc, 7.f);
  __syncthreads(); writeT(Ts, acc, w, l, 1.f); __syncthreads();
  multAr(Ts, 0, bw, l, acc);                   // c
  polyaxpy(poly, acc, -1.f);
  __syncthreads();
  writeT(Ts, poly, w, l, 0.25f);               // g1 -> Ts
  stage256(XT + (long)batch*65536, Wf, w, l);  // X^T over W5
  __syncthreads();
  loadBf(Wf, w, l, bw);
  multAr(Ts, 0, bw, l, acc);                   // u = g1@X
  const float s0 = scal[0];
  {
    const int q=l>>4, ln=l&15, wn0=w*32;
    u16* ob = uT + (long)batch*8192;
    #pragma unroll
    for (int mt=0;mt<2;mt++)
    #pragma unroll
    for (int nt=0;nt<2;nt++)
    #pragma unroll
    for (int r=0;r<4;r++){
      int row = mt*16 + q*4 + r;
      int col = wn0 + nt*16 + ln;
      ob[(long)row*256 + col] = f2bf(acc[mt][nt][r]*s0);
    }
  }
}

// ---------------------------------------------------------------------------
// Merged attn2 + attn3v (independent; grid (16,32): x<8 attn2, x>=8 attn3v)
// ---------------------------------------------------------------------------
__global__ __launch_bounds__(256)
void kattn23(const u16* __restrict__ ql, const u16* __restrict__ kl,
             u16* __restrict__ X, u16* __restrict__ XT, float* __restrict__ cs_p,
             const u16* __restrict__ kk, const u16* __restrict__ vv,
             float* __restrict__ num_p, float* __restrict__ den_p)
{
  __shared__ __align__(16) u16 Pbuf[4][64][40];
  __shared__ __align__(16) u16 vT[32][40];
  __shared__ float qrow[32][33];
  __shared__ float psum[32][4];
  __shared__ float rsum[32];
  int bh = blockIdx.y;
  int tid = threadIdx.x, w = tid>>6, l = tid&63, q = l>>4, ln = l&15;

  if (blockIdx.x < 8){
    int r0 = blockIdx.x*32;
    int c = tid;
    #pragma unroll
    for (int i=0;i<4;i++){
      int e = c*4+i; int rr = e>>5, dd = e&31;
      qrow[rr][dd] = bf2f(ql[((long)bh*256 + r0+rr)*32 + dd]);
    }
    float kc[32];
    {
      const u16* kp = kl + ((long)bh*256 + c)*32;
      #pragma unroll
      for (int d=0;d<32;d++) kc[d] = bf2f(kp[d]);
    }
    __syncthreads();
    float er[32]; float colacc = 0.f;
    for (int r=0;r<32;r++){
      float s = 0.f;
      #pragma unroll
      for (int d=0;d<32;d++) s += qrow[r][d]*kc[d];
      float e = __expf(s);
      er[r] = e;
      float wsum = e;
      #pragma unroll
      for (int m=1;m<64;m<<=1) wsum += __shfl_xor(wsum, m);
      if (l==0) psum[r][w] = wsum;
    }
    __syncthreads();
    if (c<32) rsum[c] = psum[c][0]+psum[c][1]+psum[c][2]+psum[c][3];
    __syncthreads();
    for (int r=0;r<32;r++){
      float x = er[r]/rsum[r];
      u16 xb = f2bf(x);
      X [((long)bh*256 + r0+r)*256 + c] = xb;
      XT[((long)bh*256 + c)*256 + r0+r] = xb;
      colacc += x;
    }
    cs_p[(long)blockIdx.x*8192 + bh*256 + c] = colacc;
    return;
  }

  int chunk = blockIdx.x - 8;
  f32x4 z4; z4[0]=0.f; z4[1]=0.f; z4[2]=0.f; z4[3]=0.f;
  f32x4 acc[4][2]; f32x4 dacc[4];
  #pragma unroll
  for (int mt=0;mt<4;mt++){ dacc[mt]=z4; acc[mt][0]=z4; acc[mt][1]=z4; }
  const u16* qlb = ql + (long)bh*8192;
  const u16* kb  = kk + (long)bh*131072;
  const u16* vb  = vv + (long)bh*131072;
  int vn = tid>>3, vd = (tid&7)*4;
  for (int s=0;s<16;s++){
    int n0 = chunk*512 + s*32;
    ushort4 vx = *(const ushort4*)(vb + (long)(n0+vn)*32 + vd);
    vT[vd+0][vn]=vx.x; vT[vd+1][vn]=vx.y; vT[vd+2][vn]=vx.z; vT[vd+3][vn]=vx.w;
    __syncthreads();
    s16x8 bk[2];
    #pragma unroll
    for (int nt=0;nt<2;nt++) bk[nt] = *(const s16x8*)(kb + (long)(n0 + nt*16 + ln)*32 + q*8);
    #pragma unroll
    for (int mt=0;mt<4;mt++){
      s16x8 aq = *(const s16x8*)(qlb + (long)(w*64 + mt*16 + ln)*32 + q*8);
      #pragma unroll
      for (int nt=0;nt<2;nt++){
        f32x4 sf = MFMA16(aq, bk[nt], z4);
        f32x4 ef;
        #pragma unroll
        for (int r=0;r<4;r++) ef[r] = __expf(sf[r]);
        dacc[mt] += ef;
        #pragma unroll
        for (int r=0;r<4;r++) Pbuf[w][mt*16 + q*4 + r][nt*16 + ln] = f2bf(ef[r]);
      }
    }
    #pragma unroll
    for (int mt=0;mt<4;mt++){
      s16x8 ap = *(const s16x8*)&Pbuf[w][mt*16 + ln][q*8];
      #pragma unroll
      for (int nt=0;nt<2;nt++){
        s16x8 bv = *(const s16x8*)&vT[nt*16 + ln][q*8];
        acc[mt][nt] = MFMA16(ap, bv, acc[mt][nt]);
      }
    }
    __syncthreads();
  }
  #pragma unroll
  for (int mt=0;mt<4;mt++)
    #pragma unroll
    for (int r=0;r<4;r++){
      float x = dacc[mt][r];
      x += __shfl_xor(x,1); x += __shfl_xor(x,2); x += __shfl_xor(x,4); x += __shfl_xor(x,8);
      dacc[mt][r] = x;
    }
  long pbase = (long)(chunk*32 + bh);
  #pragma unroll
  for (int mt=0;mt<4;mt++)
    #pragma unroll
    for (int nt=0;nt<2;nt++)
      #pragma unroll
      for (int r=0;r<4;r++){
        int mg = w*64 + mt*16 + q*4 + r;
        num_p[pbase*8192 + (long)mg*32 + nt*16 + ln] = acc[mt][nt][r];
      }
  if (ln==0){
    #pragma unroll
    for (int mt=0;mt<4;mt++)
      #pragma unroll
      for (int r=0;r<4;r++)
        den_p[pbase*256 + w*64 + mt*16 + q*4 + r] = dacc[mt][r];
  }
}

// ---------------------------------------------------------------------------
// attn1 fused + depthwise residual conv
// ---------------------------------------------------------------------------
__global__ __launch_bounds__(256)
void kattn1u(const u16* __restrict__ qq, const u16* __restrict__ kl, const u16* __restrict__ uT,
             const u16* __restrict__ vv, const float* __restrict__ rw,
             u16* __restrict__ aoutb)
{
  int nch = blockIdx.x, bh = blockIdx.y;
  int b = bh>>3, h = bh&7;
  int tid = threadIdx.x, w = tid>>6, l = tid&63, q = l>>4, ln = l&15;
  __shared__ __align__(16) u16 Pbuf[4][32][40];
  __shared__ __align__(16) u16 vtile[160][36];
  int r0g = nch*128;
  const u16* vb = vv + (long)bh*131072;
  #pragma unroll
  for (int it=0; it<5; it++){
    int slot = tid + it*256;
    int rr = slot>>3, c = (slot&7)*4;
    int s = r0g - 16 + rr;
    ushort4 val; val.x=0; val.y=0; val.z=0; val.w=0;
    if (s>=0 && s<4096) val = *(const ushort4*)(vb + (long)s*32 + c);
    *(ushort4*)&vtile[rr][c] = val;
  }
  __syncthreads();

  f32x4 z4; z4[0]=0.f; z4[1]=0.f; z4[2]=0.f; z4[3]=0.f;
  f32x4 acc[2][2]; f32x4 dacc[2];
  #pragma unroll
  for (int mt=0;mt<2;mt++){ dacc[mt]=z4; acc[mt][0]=z4; acc[mt][1]=z4; }
  const u16* qb  = qq + (long)bh*131072;
  const u16* klb = kl + (long)bh*8192;
  const u16* ub  = uT + (long)bh*8192;
  int r0 = r0g + w*32;
  for (int s=0;s<8;s++){
    s16x8 bk[2];
    #pragma unroll
    for (int nt=0;nt<2;nt++) bk[nt] = *(const s16x8*)(klb + (long)(s*32 + nt*16 + ln)*32 + q*8);
    #pragma unroll
    for (int mt=0;mt<2;mt++){
      s16x8 aq = *(const s16x8*)(qb + (long)(r0 + mt*16 + ln)*32 + q*8);
      #pragma unroll
      for (int nt=0;nt<2;nt++){
        f32x4 sf = MFMA16(aq, bk[nt], z4);
        f32x4 ef;
        #pragma unroll
        for (int r=0;r<4;r++) ef[r] = __expf(sf[r]);
        dacc[mt] += ef;
        #pragma unroll
        for (int r=0;r<4;r++) Pbuf[w][mt*16 + q*4 + r][nt*16 + ln] = f2bf(ef[r]);
      }
    }
    #pragma unroll
    for (int mt=0;mt<2;mt++){
      s16x8 ap = *(const s16x8*)&Pbuf[w][mt*16 + ln][q*8];
      #pragma unroll
      for (int nt=0;nt<2;nt++){
        s16x8 bu = *(const s16x8*)(ub + (long)(nt*16 + ln)*256 + s*32 + q*8);
        acc[mt][nt] = MFMA16(ap, bu, acc[mt][nt]);
      }
    }
  }
  #pragma unroll
  for (int mt=0;mt<2;mt++)
    #pragma unroll
    for (int r=0;r<4;r++){
      float x = dacc[mt][r];
      x += __shfl_xor(x,1); x += __shfl_xor(x,2); x += __shfl_xor(x,4); x += __shfl_xor(x,8);
      dacc[mt][r] = x;
    }

  const float* wp = rw + h*33;
  float w_[33];
  #pragma unroll
  for (int j=0;j<33;j++) w_[j] = wp[j];

  #pragma unroll
  for (int mt=0;mt<2;mt++){
    int nl = w*32 + mt*16 + q*4;
    #pragma unroll
    for (int nt=0;nt<2;nt++){
      int d = nt*16 + ln;
      float vvv[36];
      #pragma unroll
      for (int j=0;j<36;j++) vvv[j] = bf2f(vtile[nl + j][d]);
      #pragma unroll
      for (int r=0;r<4;r++){
        float cv = 0.f;
        #pragma unroll
        for (int j=0;j<33;j++) cv += w_[j]*vvv[r+j];
        int n = r0 + mt*16 + q*4 + r;
        long oidx = ((long)b*4096 + n)*256 + h*32 + d;
        aoutb[oidx] = f2bf(acc[mt][nt][r]/dacc[mt][r] + cv);
      }
    }
  }
}

// ---------------------------------------------------------------------------
// Merged: LN(x) (blocks 0..4095) + weight transpose/cast (blocks 4096..5119)
// ---------------------------------------------------------------------------
__global__ __launch_bounds__(256)
void kcvtln(const float* __restrict__ xin, const float* __restrict__ lg, const float* __restrict__ lb,
            u16* __restrict__ xn,
            const float* __restrict__ wqkv, const float* __restrict__ wout,
            const float* __restrict__ w1, const float* __restrict__ w2,
            u16* __restrict__ wqkvT, u16* __restrict__ woutT,
            u16* __restrict__ w1T, u16* __restrict__ w2T)
{
  __shared__ float t[32][33];
  int z = blockIdx.x;
  if (z < 4096){
    int w = threadIdx.x>>6, l = threadIdx.x&63;
    long row = (long)z*4 + w;
    float4 v = ((const float4*)(xin + row*256))[l];
    float s = v.x+v.y+v.z+v.w;
    #pragma unroll
    for (int m=1;m<64;m<<=1) s += __shfl_xor(s, m);
    float mu = s*(1.0f/256.0f);
    float dx=v.x-mu, dy=v.y-mu, dz=v.z-mu, dw=v.w-mu;
    float s2 = dx*dx+dy*dy+dz*dz+dw*dw;
    #pragma unroll
    for (int m=1;m<64;m<<=1) s2 += __shfl_xor(s2, m);
    float rs = rsqrtf(s2*(1.0f/256.0f) + 1e-5f);
    float4 gg = ((const float4*)lg)[l];
    float4 bb = ((const float4*)lb)[l];
    ushort4 o;
    o.x = f2bf(dx*rs*gg.x + bb.x);
    o.y = f2bf(dy*rs*gg.y + bb.y);
    o.z = f2bf(dz*rs*gg.z + bb.z);
    o.w = f2bf(dw*rs*gg.w + bb.w);
    *(ushort4*)(xn + row*256 + l*4) = o;
    return;
  }
  z -= 4096;
  const float* src; u16* dst; int K, Nn, bx, by;
  if (z < 384){      int i=z/192, r=z%192; src=wqkv+(long)i*196608; dst=wqkvT+(long)i*196608; K=256; Nn=768; bx=r%24; by=r/24; }
  else if (z < 512){ int zz=z-384; int i=zz/64, r=zz%64; src=wout+(long)i*65536; dst=woutT+(long)i*65536; K=256; Nn=256; bx=r%8; by=r/8; }
  else if (z < 768){ int zz=z-512; int i=zz/128, r=zz%128; src=w1+(long)i*131072; dst=w1T+(long)i*131072; K=256; Nn=512; bx=r%16; by=r/16; }
  else {             int zz=z-768; int i=zz/128, r=zz%128; src=w2+(long)i*131072; dst=w2T+(long)i*131072; K=512; Nn=256; bx=r%8; by=r/8; }
  int n0 = bx*32, k0 = by*32;
  int tx = threadIdx.x&31, ty = threadIdx.x>>5;
  #pragma unroll
  for (int i=0;i<4;i++) t[ty+i*8][tx] = src[(long)(k0+ty+i*8)*Nn + n0+tx];
  __syncthreads();
  #pragma unroll
  for (int i=0;i<4;i++) dst[(long)(n0+ty+i*8)*K + k0+tx] = f2bf(t[tx][ty+i*8]);
}

// ---------------------------------------------------------------------------
extern "C" void kernel_launch(void* const* d_in, const int* in_sizes, int n_in,
                              void* d_out, int out_size, void* d_ws, size_t ws_size,
                              hipStream_t stream)
{
  const float* x    = (const float*)d_in[0];
  const float* ln1g = (const float*)d_in[1];
  const float* ln1b = (const float*)d_in[2];
  const float* wqkv = (const float*)d_in[3];
  const float* wout = (const float*)d_in[4];
  const float* bout = (const float*)d_in[5];
  const float* resw = (const float*)d_in[6];
  const float* ln2g = (const float*)d_in[7];
  const float* ln2b = (const float*)d_in[8];
  const float* w1   = (const float*)d_in[9];
  const float* b1   = (const float*)d_in[10];
  const float* w2   = (const float*)d_in[11];
  const float* b2   = (const float*)d_in[12];
  float* y = (float*)d_out;
  char* ws = (char*)d_ws;

  u16* xn    = (u16*)(ws + 0);
  u16* qb    = (u16*)(ws + 8388608);
  u16* kb    = (u16*)(ws + 16777216);
  u16* vb    = (u16*)(ws + 25165824);
  u16* ql    = (u16*)(ws + 33554432);
  u16* kl    = (u16*)(ws + 34078720);
  u16* X     = (u16*)(ws + 34603008);
  u16* XT    = (u16*)(ws + 38797312);     // X^T (B-operand of final U GEMM)
  u16* h0b   = (u16*)(ws + 42991616);     // h0 [32][32][256] bf16 (512 KB)
  // pinv work region
  u16* WA    = (u16*)(ws + 51380224);
  u16* WB    = (u16*)(ws + 55574528);
  u16* hA    = (u16*)(ws + 68157440);     // thin h buffers [32][32][256]
  u16* hB    = (u16*)(ws + 72351744);
  float* num_p = (float*)(ws + 76546048);  // 8 MB
  float* den_p = (float*)(ws + 84934656);
  float* cs_p  = (float*)(ws + 85196800);
  float* scal  = (float*)(ws + 85458944);
  u16* uT    = (u16*)(ws + 85459200);
  u16* aoutb = (u16*)(ws + 85983488);
  u16* wqkvT = (u16*)(ws + 94372096);
  u16* woutT = (u16*)(ws + 95158528);
  u16* w1T   = (u16*)(ws + 95420672);
  u16* w2T   = (u16*)(ws + 95944960);
  u16* hdn   = (u16*)(ws + 51380224);      // overlays WA/WB (dead by FFN)

  (void)in_sizes; (void)n_in; (void)out_size; (void)ws_size;

  // LN(x) + weight cvt in one launch
  kcvtln<<<5120,256,0,stream>>>(x, ln1g, ln1b, xn,
      wqkv, wout, w1, w2, wqkvT, woutT, w1T, w2T);

  for (int i=0;i<2;i++){
    // xn: i==0 from kcvtln; i==1 from previous FFN2's fused LN epilogue
    kgemm2<EPI_QKV><<<dim3(128,6),256,0,stream>>>(xn, wqkvT + (long)i*196608, 256, 256, 256,
        nullptr, nullptr, 0, qb,kb,vb, ql,kl);
    kattn23<<<dim3(16,32),256,0,stream>>>(ql, kl, X, XT, cs_p, kb, vb, num_p, den_p);

    // ---- pinv: kw0 (scal + W0 + h0) -> 5x kiter -> ktail (g1 chain + U) ----
    kw0<<<256,512,0,stream>>>(cs_p, scal, num_p, den_p, X, WA, h0b);
    u16 *Wi = WA, *Wo = WB, *hi = h0b, *ho = hA;
    for (int it=0; it<5; it++){
      kiter<<<256,512,0,stream>>>(Wi, Wo, hi, ho);
      u16* t = Wi; Wi = Wo; Wo = t;
      hi = ho; ho = (ho == hA) ? hB : hA;
    }
    ktail<<<32,512,0,stream>>>(Wi, hi, XT, scal, uT);

    kattn1u<<<dim3(32,32),256,0,stream>>>(qb, kl, uT, vb, resw + i*264, aoutb);
    // wout GEMM + residual + LN2 fused -> y (f32) + xn (bf16 for FFN1)
    kgemmLN<<<256,256,0,stream>>>(aoutb, woutT + (long)i*65536, 256,
        bout + i*256, i==0 ? x : y, y, ln2g + i*256, ln2b + i*256, xn);
    kgemm2<EPI_BIAS_GELU><<<dim3(128,4),256,0,stream>>>(xn, w1T + (long)i*131072, 256, 256, 256,
        b1 + i*512, hdn, 512, nullptr,nullptr,nullptr, nullptr,nullptr);
    // FFN2 GEMM + residual + LN1(next) fused -> y + xn (for next QKV; dead on i==1)
    kgemmLN<<<256,256,0,stream>>>(hdn, w2T + (long)i*131072, 512,
        b2 + i*256, y, y, ln1g + 256, ln1b + 256, xn);
  }
}